// Round 10
// baseline (494.504 us; speedup 1.0000x reference)
//
#include <hip/hip_runtime.h>
#include <hip/hip_bf16.h>
#include <math.h>

#define DIM    256
#define DEPTH  5
#define FANOUT 10
#define VOCAB  257
#define BB     16
#define TT     2048
#define NEXP   8
#define HID    512
#define TOPK   2
#define CAP    5   // ceil(16*2/8*1.1)

__device__ __forceinline__ float sigm(float x) { return 1.f / (1.f + expf(-x)); }

// 256x256 matvec partial: 1024 threads = 16 ksegs x 64 col-quads.
// Depth-8 float4 batches inside a KEPT loop (#pragma unroll 1): 2 latency
// exposures per matvec. R1-R3 lesson: fully-unrolled forms get ALL loads
// hoisted and spill 10MB/dispatch; only a real loop boundary stops the hoist.
__device__ __forceinline__ void mv8x2(const float* sv, const float* __restrict__ W,
                                      int kseg, int cq, float red[16][DIM]) {
  const float* Wp = W + (size_t)kseg * 16 * DIM + cq * 4;
  float4 acc = {0.f, 0.f, 0.f, 0.f};
#pragma unroll 1
  for (int h = 0; h < 2; ++h) {
    float4 wv[8];
#pragma unroll
    for (int i = 0; i < 8; ++i)
      wv[i] = *(const float4*)(Wp + (size_t)(h * 8 + i) * DIM);
#pragma unroll
    for (int i = 0; i < 8; ++i) {
      float s = sv[kseg * 16 + h * 8 + i];
      acc.x = fmaf(s, wv[i].x, acc.x);
      acc.y = fmaf(s, wv[i].y, acc.y);
      acc.z = fmaf(s, wv[i].z, acc.z);
      acc.w = fmaf(s, wv[i].w, acc.w);
    }
    __builtin_amdgcn_sched_barrier(0);
  }
  *(float4*)&red[kseg][cq * 4] = acc;
}

__device__ __forceinline__ float sum16(const float red[16][DIM], int d) {
  float s = 0.f;
#pragma unroll
  for (int g = 0; g < 16; ++g) s += red[g][d];
  return s;
}

// ------ collapsed fractal + fused-weight precompute + root2 init --------------
// Grid = 256 blocks, role = bx&7 (XCD id, round-robin block->XCD mapping):
//   xcd 0, slot 0..15  : the 16 real per-batch chains (11 matvec units after
//                        the v*pch fusion; was 15) - all on XCD0's L2 (R9).
//   xcd 0, slot 16..31 : producers: W_l = v_w*diag(sigm(dg_l))*pch_w and
//                        b_l = (sigm(dg_l)*v_b)@pch_w + pch_b, written into
//                        ws (XCD0's L2, same-XCD as consumers -> coherent via
//                        shared L2); flag-gated. Then warm remaining weights.
//   xcd 1, slot 0..15  : token-CSR build. slot 16..31: hw1/hw2 warm for logits.
//   xcd >= 2           : warm ew1/ew2 into their L2s DURING the chain (k_moe
//                        starts warm).
// R9 lesson: FETCH dropped 9.5->1.3MB with no dur change -> fills were already
// hidden; the 52us is the serial chain itself. This round removes 4 matvec
// units + 8 barriers from it.
__global__ void __launch_bounds__(1024) k_fractal(
    const int* __restrict__ tokens, const float* __restrict__ embed,
    const float* __restrict__ pin_w, const float* __restrict__ pin_b,
    const float* __restrict__ pch_w, const float* __restrict__ pch_b,
    const float* __restrict__ depth_bias,
    const float* __restrict__ v_w, const float* __restrict__ v_b,
    const float* __restrict__ o_w, const float* __restrict__ o_b,
    const float* __restrict__ level_gate, const float* __restrict__ depth_gate,
    const float* __restrict__ in_proj_w, const float* __restrict__ in_proj_b,
    const float* __restrict__ out_proj_w, const float* __restrict__ out_proj_b,
    const float* __restrict__ ln_g, const float* __restrict__ ln_b,
    const float* __restrict__ ic_gate,
    const float* __restrict__ ew1, const float* __restrict__ ew2,
    const float* __restrict__ hw1, const float* __restrict__ hw2,
    float* __restrict__ rootA, float* __restrict__ root2,
    int* __restrict__ bidx, int* __restrict__ boff,
    float* __restrict__ wsW, float* __restrict__ wsb,
    int* __restrict__ wflag) {
  int bx = blockIdx.x;
  int tid = threadIdx.x;
  int xcd = bx & 7, slot = bx >> 3;
  __shared__ int cnt[VOCAB];
  __shared__ float sv[DIM];
  __shared__ float basev[DIM];
  __shared__ float ym[DEPTH][DIM];
  __shared__ float q0v[DIM], kh[DEPTH][DIM], vh[DEPTH][DIM];
  __shared__ float red11[4][11][DIM];   // in_proj reduction; also aliases red16
  __shared__ float zsv[DIM];
  __shared__ float aw[16];
  __shared__ float redl[8];
  __shared__ int offb[VOCAB + 1];
  __shared__ int woff[VOCAB];
  __shared__ float vg[64][DIM];         // producer: v_w rows * g  (64KB)
  __shared__ float gl[DIM];
  float (*red16)[DIM] = reinterpret_cast<float(*)[DIM]>(&red11[0][0][0]); // 16KB of 44KB

  if (xcd >= 2) {
    // ---- warm ew1/ew2 into this XCD's L2 during the chain (for k_moe) ----
    int wi = (xcd - 2) * 32 + slot;     // 0..191
    int r = wi % 128;
    const float* W = (r < 64) ? ew1 + (size_t)r * 16384
                              : ew2 + (size_t)(r - 64) * 16384;
    const float4* src = (const float4*)W + tid;
    float sx = 0.f, sy = 0.f, sz = 0.f, sw = 0.f;
#pragma unroll
    for (int k2 = 0; k2 < 4; ++k2) {
      float4 v = src[k2 * 1024];
      sx += v.x; sy += v.y; sz += v.z; sw += v.w;
    }
    asm volatile("" :: "v"(sx), "v"(sy), "v"(sz), "v"(sw));
    return;
  }
  if (xcd == 1) {
    if (slot < BB) {
      // ---- token CSR for batch b: off the chain's critical path ----
      int b = slot;
      for (int i = tid; i < VOCAB; i += 1024) cnt[i] = 0;
      __syncthreads();
      for (int t = tid; t < TT; t += 1024) atomicAdd(&cnt[tokens[b * TT + t]], 1);
      __syncthreads();
      if (tid == 0) {
        int a = 0;
        for (int v = 0; v < VOCAB; ++v) { offb[v] = a; a += cnt[v]; }
        offb[VOCAB] = a;              // == TT
      }
      __syncthreads();
      if (tid <= VOCAB) boff[b * (VOCAB + 1) + tid] = offb[tid];
      if (tid < VOCAB) woff[tid] = offb[tid];
      __syncthreads();
      for (int t = tid; t < TT; t += 1024) {
        int tok = tokens[b * TT + t];
        int p = atomicAdd(&woff[tok], 1);
        bidx[b * TT + p] = t;         // bucket order arbitrary; output order-invariant
      }
    } else {
      // warm hw1/hw2/embed for k_logits (XCD1's share; k_moe warms the rest)
      int r = (slot - BB) % 12;
      const float* W;
      if (r < 4)       W = hw1   + (size_t)r * 16384;
      else if (r < 8)  W = hw2   + (size_t)(r - 4) * 16384;
      else             W = embed + (size_t)(r - 8) * 16384;
      const float4* src = (const float4*)W + tid;
      float sx = 0.f, sy = 0.f, sz = 0.f, sw = 0.f;
#pragma unroll
      for (int k2 = 0; k2 < 4; ++k2) {
        float4 v = src[k2 * 1024];
        sx += v.x; sy += v.y; sz += v.z; sw += v.w;
      }
      asm volatile("" :: "v"(sx), "v"(sy), "v"(sz), "v"(sw));
    }
    return;
  }
  if (slot >= BB) {
    // ---- producer: W_l (64 rows) + b_l; same XCD as the chains ----
    int p = slot - BB;                 // 0..15
    int l = p & 3, rowbase = (p >> 2) * 64;
    int j = tid & 255, iq = tid >> 8;  // iq 0..3 -> 16 rows each
    if (tid < DIM) gl[tid] = sigm(depth_gate[l * DIM + tid]);
    __syncthreads();
    for (int idx = tid; idx < 64 * 64; idx += 1024) {   // float4 units
      int i = idx >> 6, c4 = idx & 63;
      float4 v = *(const float4*)&v_w[(size_t)(rowbase + i) * DIM + c4 * 4];
      v.x *= gl[c4 * 4];     v.y *= gl[c4 * 4 + 1];
      v.z *= gl[c4 * 4 + 2]; v.w *= gl[c4 * 4 + 3];
      *(float4*)&vg[i][c4 * 4] = v;
    }
    if (tid < DIM) sv[tid] = v_b[tid] * gl[tid];        // for b_l
    __syncthreads();
    float acc[16];
#pragma unroll
    for (int r = 0; r < 16; ++r) acc[r] = 0.f;
    float bacc = 0.f;
#pragma unroll 1
    for (int kb = 0; kb < DIM; kb += 16) {              // 16-deep load batches
      float wv[16];
#pragma unroll
      for (int i = 0; i < 16; ++i) wv[i] = pch_w[(size_t)(kb + i) * DIM + j];
#pragma unroll
      for (int i = 0; i < 16; ++i) {
        int k = kb + i;
        float w = wv[i];
#pragma unroll
        for (int r = 0; r < 16; ++r)
          acc[r] = fmaf(vg[iq * 16 + r][k], w, acc[r]); // LDS broadcast (j-indep)
        bacc = fmaf(sv[k], w, bacc);
      }
      __builtin_amdgcn_sched_barrier(0);
    }
    float* Wl = wsW + (size_t)l * 65536;
#pragma unroll
    for (int r = 0; r < 16; ++r)
      Wl[(size_t)(rowbase + iq * 16 + r) * DIM + j] = acc[r];
    if (iq == 0 && (p >> 2) == 0)
      wsb[l * DIM + j] = bacc + pch_b[j];
    __threadfence();
    __syncthreads();
    if (tid == 0) atomicAdd(wflag, 1);
    // then warm the chain's remaining weights (o, in_proj, out_proj, pin, embed)
    {
      float sx = 0.f, sy = 0.f, sz = 0.f, sw = 0.f;
#pragma unroll 1
      for (int q = 0; q < 2; ++q) {
        int r = p * 2 + q;
        if (r >= 28) break;
        const float* W;
        if (r < 4)       W = o_w        + (size_t)r * 16384;
        else if (r < 16) W = in_proj_w  + (size_t)(r - 4) * 16384;
        else if (r < 20) W = out_proj_w + (size_t)(r - 16) * 16384;
        else if (r < 24) W = pin_w      + (size_t)(r - 20) * 16384;
        else             W = embed      + (size_t)(r - 24) * 16384;
        const float4* src = (const float4*)W + tid;
#pragma unroll
        for (int k2 = 0; k2 < 4; ++k2) {
          float4 v = src[k2 * 1024];
          sx += v.x; sy += v.y; sz += v.z; sw += v.w;
        }
      }
      asm volatile("" :: "v"(sx), "v"(sy), "v"(sz), "v"(sw));
    }
    return;
  }

  int b = slot;
  int d = tid & 255;
  int ks = tid >> 8;       // 0..3 (consumer / in_proj layout)
  int k0 = ks * 64;
  int kseg = tid >> 6;     // 0..15 (mv8x2 layout)
  int cq = tid & 63;

  // ---- context = (histogram @ embed) / T, branch-free ----
  for (int i = tid; i < VOCAB; i += 1024) cnt[i] = 0;
  __syncthreads();
  for (int t = tid; t < TT; t += 1024) atomicAdd(&cnt[tokens[b * TT + t]], 1);
  __syncthreads();
  {
    const float* Ep = embed + (size_t)kseg * 16 * DIM + cq * 4;
    float4 acc = {0.f, 0.f, 0.f, 0.f};
#pragma unroll 1
    for (int h = 0; h < 2; ++h) {
      float4 ev[8];
#pragma unroll
      for (int i = 0; i < 8; ++i)
        ev[i] = *(const float4*)(Ep + (size_t)(h * 8 + i) * DIM);
#pragma unroll
      for (int i = 0; i < 8; ++i) {
        float cv = (float)cnt[kseg * 16 + h * 8 + i];
        acc.x = fmaf(cv, ev[i].x, acc.x);
        acc.y = fmaf(cv, ev[i].y, acc.y);
        acc.z = fmaf(cv, ev[i].z, acc.z);
        acc.w = fmaf(cv, ev[i].w, acc.w);
      }
      __builtin_amdgcn_sched_barrier(0);
    }
    *(float4*)&red16[kseg][cq * 4] = acc;
  }
  __syncthreads();
  if (ks == 0) {
    float s = sum16(red16, d);
    s = fmaf((float)cnt[256], embed[(size_t)256 * DIM + d], s);
    sv[d] = s * (1.0f / (float)TT);
  }
  __syncthreads();

  mv8x2(sv, pin_w, kseg, cq, red16);
  __syncthreads();
  if (ks == 0) {
    float base = sum16(red16, d) + pin_b[d];
    basev[d] = base;
    float u = (base + depth_bias[4 * DIM + d] + pch_b[d]) * sigm(level_gate[4]);
    sv[d] = fmaxf(u, 0.f);
  }
  __syncthreads();
  mv8x2(sv, o_w, kseg, cq, red16);
  __syncthreads();
  if (ks == 0) {
    float y = sum16(red16, d) + o_b[d];
    ym[4][d] = y;
    sv[d] = y;
  }
  __syncthreads();
  // gate on the producers (done ~6us in; we arrive here ~9us in -> ~0 wait)
  if (tid == 0) {
    while (__hip_atomic_load(wflag, __ATOMIC_ACQUIRE, __HIP_MEMORY_SCOPE_AGENT) < 16) {}
  }
  __syncthreads();
  for (int l = 3; l >= 0; --l) {
    mv8x2(sv, wsW + (size_t)l * 65536, kseg, cq, red16);   // fused v*g*pch
    __syncthreads();
    if (ks == 0) {
      float t = sum16(red16, d) + wsb[l * DIM + d];
      float u = (basev[d] + depth_bias[l * DIM + d] + t) * sigm(level_gate[l]);
      sv[d] = fmaxf(u, 0.f);
    }
    __syncthreads();
    mv8x2(sv, o_w, kseg, cq, red16);
    __syncthreads();
    if (ks == 0) {
      float y = sum16(red16, d) + o_b[d];
      ym[l][d] = y;
      sv[d] = y;
    }
    __syncthreads();
  }
  // ---- in_proj, ALL levels in ONE pass over the weights (8-deep batches) ----
  {
    float aq = 0.f;
    float ak0 = 0.f, ak1 = 0.f, ak2 = 0.f, ak3 = 0.f, ak4 = 0.f;
    float av0 = 0.f, av1 = 0.f, av2 = 0.f, av3 = 0.f, av4 = 0.f;
#pragma unroll
    for (int h = 0; h < 8; ++h) {
      int kb = k0 + h * 8;
      float wq[8], wk[8], wv8[8];
#pragma unroll
      for (int i = 0; i < 8; ++i) {
        const float* wrow = in_proj_w + (size_t)(kb + i) * 768;
        wq[i] = wrow[d]; wk[i] = wrow[256 + d]; wv8[i] = wrow[512 + d];
      }
#pragma unroll
      for (int i = 0; i < 8; ++i) {
        float z0 = ym[0][kb + i];
        aq  = fmaf(z0, wq[i], aq);
        ak0 = fmaf(z0, wk[i], ak0);
        av0 = fmaf(z0, wv8[i], av0);
        float z1 = ym[1][kb + i];
        ak1 = fmaf(z1, wk[i], ak1);
        av1 = fmaf(z1, wv8[i], av1);
        float z2 = ym[2][kb + i];
        ak2 = fmaf(z2, wk[i], ak2);
        av2 = fmaf(z2, wv8[i], av2);
        float z3 = ym[3][kb + i];
        ak3 = fmaf(z3, wk[i], ak3);
        av3 = fmaf(z3, wv8[i], av3);
        float z4 = ym[4][kb + i];
        ak4 = fmaf(z4, wk[i], ak4);
        av4 = fmaf(z4, wv8[i], av4);
      }
    }
    red11[ks][0][d] = ak0; red11[ks][1][d] = ak1; red11[ks][2][d] = ak2;
    red11[ks][3][d] = ak3; red11[ks][4][d] = ak4;
    red11[ks][5][d] = av0; red11[ks][6][d] = av1; red11[ks][7][d] = av2;
    red11[ks][8][d] = av3; red11[ks][9][d] = av4;
    red11[ks][10][d] = aq;
  }
  __syncthreads();
  for (int idx = tid; idx < 11 * DIM; idx += 1024) {
    int c = idx >> 8, dd = idx & 255;
    float sum = red11[0][c][dd] + red11[1][c][dd] + red11[2][c][dd] + red11[3][c][dd];
    if (c < 5)       kh[c][dd]     = sum + in_proj_b[256 + dd];
    else if (c < 10) vh[c - 5][dd] = sum + in_proj_b[512 + dd];
    else             q0v[dd]       = sum + in_proj_b[dd];
  }
  __syncthreads();
  {
    int wid = tid >> 6;
    if (wid < 10) {
      int h = wid / 5, l = wid - h * 5;
      int lane = tid & 63;
      float s = q0v[h * 128 + lane] * kh[l][h * 128 + lane];
      s = fmaf(q0v[h * 128 + 64 + lane], kh[l][h * 128 + 64 + lane], s);
      for (int o = 32; o > 0; o >>= 1) s += __shfl_down(s, o, 64);
      if (lane == 0) aw[wid] = s * 0.08838834764831845f;  // 1/sqrt(128)
    }
  }
  __syncthreads();
  if (tid < 2) {
    float m = aw[tid * 5];
    for (int l = 1; l < 5; ++l) m = fmaxf(m, aw[tid * 5 + l]);
    float e[5], ssum = 0.f;
    for (int l = 0; l < 5; ++l) { e[l] = expf(aw[tid * 5 + l] - m); ssum += e[l]; }
    for (int l = 0; l < 5; ++l) aw[tid * 5 + l] = e[l] / ssum;
  }
  __syncthreads();
  if (ks == 0) {
    int h = d >> 7;
    float z2 = 0.f;
    for (int l = 0; l < 5; ++l) z2 = fmaf(aw[h * 5 + l], vh[l][d], z2);
    sv[d] = z2;
  }
  __syncthreads();
  mv8x2(sv, out_proj_w, kseg, cq, red16);
  __syncthreads();
  if (ks == 0) {
    float z2p = sum16(red16, d) + out_proj_b[d];
    zsv[d] = ym[0][d] + z2p;
  }
  __syncthreads();
  float zs = 0.f, df = 0.f, mu = 0.f;
  if (tid < 256) {
    zs = zsv[tid];
    float v = zs;
    for (int o = 32; o > 0; o >>= 1) v += __shfl_down(v, o, 64);
    if ((tid & 63) == 0) redl[tid >> 6] = v;
  }
  __syncthreads();
  if (tid < 256) {
    mu = (redl[0] + redl[1] + redl[2] + redl[3]) * (1.f / 256.f);
    df = zs - mu;
  }
  __syncthreads();
  if (tid < 256) {
    float v = df * df;
    for (int o = 32; o > 0; o >>= 1) v += __shfl_down(v, o, 64);
    if ((tid & 63) == 0) redl[tid >> 6] = v;
  }
  __syncthreads();
  if (tid < 256) {
    float var = (redl[0] + redl[1] + redl[2] + redl[3]) * (1.f / 256.f);
    float zn = df / sqrtf(var + 1e-5f) * ln_g[tid] + ln_b[tid];
    float r = ym[0][tid] + sigm(ic_gate[0]) * zn;
    rootA[b * DIM + tid] = r;
    root2[b * DIM + tid] = r;   // experts atomically add on top
  }
}

// ---- fused MoE: gating + GEMM1 + partial-GEMM2 + combine -------------------
// Blocks 0..63 = 8 experts x 8 tiles of 64 HID cols (unchanged from R7).
// Blocks 64..255 = warmers for hw1/hw2/embed (k_logits' weights; ew1/ew2 are
// already warmed by k_fractal's xcd>=2 blocks during the chain).
__global__ void __launch_bounds__(256) k_moe(
    const float* __restrict__ rootA,
    const float* __restrict__ gate_w, const float* __restrict__ gate_b,
    const float* __restrict__ ew1, const float* __restrict__ eb1,
    const float* __restrict__ ew2, const float* __restrict__ eb2,
    const float* __restrict__ hw1, const float* __restrict__ hw2,
    const float* __restrict__ embed,
    float* __restrict__ root2) {
  int bx = blockIdx.x;
  int tid = threadIdx.x;
  if (bx >= 64) {
    int r = (bx - 64) % 12;
    const float* W;
    if (r < 4)       W = hw1   + (size_t)r * 16384;
    else if (r < 8)  W = hw2   + (size_t)(r - 4) * 16384;
    else             W = embed + (size_t)(r - 8) * 16384;
    const float4* src = (const float4*)W + tid;
    float sx = 0.f, sy = 0.f, sz = 0.f, sw = 0.f;
#pragma unroll 4
    for (int i = 0; i < 16; ++i) {
      float4 v = src[i * 256];
      sx += v.x; sy += v.y; sz += v.z; sw += v.w;
    }
    asm volatile("" :: "v"(sx), "v"(sy), "v"(sz), "v"(sw));
    return;
  }
  int e = bx >> 3, jt = bx & 7, j0 = jt * 64;
  int w = tid >> 6, lane = tid & 63;
  __shared__ float rlds[BB * DIM];      // 16KB rootA copy
  __shared__ float gwlds[DIM * NEXP];   // 8KB gate_w copy
  __shared__ float xin[CAP][DIM];
  __shared__ float red[CAP][4][64];
  __shared__ float hloc[CAP][64];
  __shared__ float sc[BB * NEXP];
  __shared__ float gs[BB * TOPK];
  __shared__ int gidx[BB * TOPK];
  __shared__ int stok[CAP];
  __shared__ float swt[CAP];
  for (int idx = tid; idx < BB * DIM / 4; idx += 256)
    *(float4*)&rlds[idx * 4] = *(const float4*)&rootA[idx * 4];
  for (int idx = tid; idx < DIM * NEXP / 4; idx += 256)
    *(float4*)&gwlds[idx * 4] = *(const float4*)&gate_w[idx * 4];
  __syncthreads();
  if (tid < BB * NEXP) {
    int b = tid >> 3, ep = tid & 7;
    float chunk[8];
#pragma unroll
    for (int g = 0; g < 8; ++g) {
      float acc = 0.f;
#pragma unroll 8
      for (int i = 0; i < 32; ++i) {
        int k = g * 32 + i;
        acc = fmaf(rlds[b * DIM + k], gwlds[k * NEXP + ep], acc);
      }
      chunk[g] = acc;
    }
    float s = gate_b[ep];
#pragma unroll
    for (int g = 0; g < 8; ++g) s += chunk[g];
    sc[tid] = s;
  }
  __syncthreads();
  if (tid < BB) {  // top-2 + softmax per batch (identical order to old k_gate)
    int bb = tid;
    int i0 = 0; float v0 = sc[bb * 8 + 0];
    for (int ee = 1; ee < 8; ++ee) { float v = sc[bb * 8 + ee]; if (v > v0) { v0 = v; i0 = ee; } }
    int i1 = -1; float v1 = -1e30f;
    for (int ee = 0; ee < 8; ++ee) {
      if (ee == i0) continue;
      float v = sc[bb * 8 + ee];
      if (v > v1) { v1 = v; i1 = ee; }
    }
    float e1v = expf(v1 - v0);
    float s = 1.f + e1v;
    gs[bb * 2 + 0] = 1.f / s;  gidx[bb * 2 + 0] = i0;
    gs[bb * 2 + 1] = e1v / s;  gidx[bb * 2 + 1] = i1;
  }
  __syncthreads();
  if (tid == 0) {  // top-CAP for own expert: bitmask, value desc / index asc
    unsigned used = 0u;
    for (int s = 0; s < CAP; ++s) {
      int bi = 0; float bv = -1e30f;
      for (int i = 0; i < 32; ++i) {
        if (used & (1u << i)) continue;
        float v = (gidx[i] == e) ? gs[i] : -1.0f;
        if (v > bv) { bv = v; bi = i; }
      }
      used |= (1u << bi);
      stok[s] = bi >> 1;
      swt[s] = bv > 0.f ? bv : 0.f;
    }
  }
  __syncthreads();
  for (int idx = tid; idx < CAP * DIM; idx += 256) {
    int s = idx >> 8, k = idx & 255;
    xin[s][k] = rlds[stok[s] * DIM + k];
  }
  __syncthreads();
  // GEMM1: this block's 64 HID cols (identical order to old k_expert1)
  {
    float a0 = 0.f, a1 = 0.f, a2 = 0.f, a3 = 0.f, a4 = 0.f;
    const float* W = ew1 + (size_t)e * DIM * HID + j0 + lane;  // row k -> +k*HID
    int kbase = w * 64;
#pragma unroll
    for (int h = 0; h < 8; ++h) {
      float wv[8];
#pragma unroll
      for (int i = 0; i < 8; ++i) wv[i] = W[(size_t)(kbase + h * 8 + i) * HID];
#pragma unroll
      for (int i = 0; i < 8; ++i) {
        int k = kbase + h * 8 + i;
        a0 = fmaf(xin[0][k], wv[i], a0);
        a1 = fmaf(xin[1][k], wv[i], a1);
        a2 = fmaf(xin[2][k], wv[i], a2);
        a3 = fmaf(xin[3][k], wv[i], a3);
        a4 = fmaf(xin[4][k], wv[i], a4);
      }
    }
    red[0][w][lane] = a0; red[1][w][lane] = a1; red[2][w][lane] = a2;
    red[3][w][lane] = a3; red[4][w][lane] = a4;
  }
  __syncthreads();
  for (int idx = tid; idx < CAP * 64; idx += 256) {
    int s = idx >> 6, j = idx & 63;
    float sum = red[s][0][j] + red[s][1][j] + red[s][2][j] + red[s][3][j]
              + eb1[e * HID + j0 + j];
    hloc[s][j] = fmaxf(sum, 0.f);
  }
  __syncthreads();
  // partial GEMM2: K = this block's 64 hid cols, d = tid (0..255)
  {
    int d = tid;
    float a0 = 0.f, a1 = 0.f, a2 = 0.f, a3 = 0.f, a4 = 0.f;
    const float* W2 = ew2 + (size_t)e * HID * DIM + (size_t)j0 * DIM + d;
#pragma unroll
    for (int h = 0; h < 8; ++h) {
      float wv[8];
#pragma unroll
      for (int i = 0; i < 8; ++i) wv[i] = W2[(size_t)(h * 8 + i) * DIM];
#pragma unroll
      for (int i = 0; i < 8; ++i) {
        int j = h * 8 + i;
        a0 = fmaf(hloc[0][j], wv[i], a0);
        a1 = fmaf(hloc[1][j], wv[i], a1);
        a2 = fmaf(hloc[2][j], wv[i], a2);
        a3 = fmaf(hloc[3][j], wv[i], a3);
        a4 = fmaf(hloc[4][j], wv[i], a4);
      }
    }
    float bias = (jt == 0) ? eb2[e * DIM + d] : 0.f;
#pragma unroll
    for (int s = 0; s < CAP; ++s) {
      float as = (s == 0) ? a0 : (s == 1) ? a1 : (s == 2) ? a2 : (s == 3) ? a3 : a4;
      float wgt = swt[s];
      if (wgt > 0.f)
        atomicAdd(&root2[stok[s] * DIM + d], (as + bias) * wgt);
    }
  }
}

// ---- logits + fused scatter: grid (257 tokens x 4 rowgroups) x 256 threads --
// R5-proven shape: 1028 blocks keeps the machine latency-tolerant; weights
// (520KB) are L2-resident so redundant reads are cheap.
__global__ void __launch_bounds__(256) k_logits(
    const float* __restrict__ embed, const float* __restrict__ root2,
    const float* __restrict__ hw1, const float* __restrict__ hb1,
    const float* __restrict__ hw2, const float* __restrict__ hb2,
    const int* __restrict__ bidx, const int* __restrict__ boff,
    float* __restrict__ out) {
  int tok = blockIdx.x, r0 = blockIdx.y * 4;
  int c = threadIdx.x;
  __shared__ float hrow[4][DIM];
  __shared__ float hid[4][DIM];
  __shared__ float tailred[4][17];
  __shared__ float tailv[4];
  {
    float ev = embed[(size_t)tok * DIM + c];
#pragma unroll
    for (int j = 0; j < 4; ++j) hrow[j][c] = ev + root2[(size_t)(r0 + j) * DIM + c];
  }
  __syncthreads();
  // GEMM1: col c over K=256, 4 rows
  {
    float a0 = hb1[c], a1 = a0, a2 = a0, a3 = a0;
    for (int kb = 0; kb < DIM; kb += 8) {
      float wv[8];
#pragma unroll
      for (int i = 0; i < 8; ++i) wv[i] = hw1[(size_t)(kb + i) * DIM + c];
#pragma unroll
      for (int i = 0; i < 8; ++i) {
        int k = kb + i;
        a0 = fmaf(hrow[0][k], wv[i], a0);
        a1 = fmaf(hrow[1][k], wv[i], a1);
        a2 = fmaf(hrow[2][k], wv[i], a2);
        a3 = fmaf(hrow[3][k], wv[i], a3);
      }
    }
    hid[0][c] = fmaxf(a0, 0.f); hid[1][c] = fmaxf(a1, 0.f);
    hid[2][c] = fmaxf(a2, 0.f); hid[3][c] = fmaxf(a3, 0.f);
  }
  __syncthreads();
  // GEMM2: cols 0..255 into registers
  float a0, a1, a2, a3;
  {
    a0 = hb2[c]; a1 = a0; a2 = a0; a3 = a0;
    for (int kb = 0; kb < DIM; kb += 8) {
      float wv[8];
#pragma unroll
      for (int i = 0; i < 8; ++i) wv[i] = hw2[(size_t)(kb + i) * VOCAB + c];
#pragma unroll
      for (int i = 0; i < 8; ++i) {
        int k = kb + i;
        a0 = fmaf(hid[0][k], wv[i], a0);
        a1 = fmaf(hid[1][k], wv[i], a1);
        a2 = fmaf(hid[2][k], wv[i], a2);
        a3 = fmaf(hid[3][k], wv[i], a3);
      }
    }
  }
  // tail column 256: 16-way K-split across first 64 threads
  if (c < 64) {
    int r = c >> 4, seg = c & 15;
    float sum = 0.f;
#pragma unroll 4
    for (int i = 0; i < 16; ++i) {
      int k = seg * 16 + i;
      sum = fmaf(hid[r][k], hw2[(size_t)k * VOCAB + 256], sum);
    }
    tailred[r][seg] = sum;
  }
  __syncthreads();
  if (c < 4) {
    float a = hb2[256];
#pragma unroll
    for (int s = 0; s < 16; ++s) a += tailred[c][s];
    tailv[c] = a;
  }
  __syncthreads();
  // fused scatter: write this row to every matching t (coalesced 1KB rows)
#pragma unroll
  for (int j = 0; j < 4; ++j) {
    int b = r0 + j;
    int s = boff[b * (VOCAB + 1) + tok];
    int e = boff[b * (VOCAB + 1) + tok + 1];
    float aj = (j == 0) ? a0 : (j == 1) ? a1 : (j == 2) ? a2 : a3;
    float tl = tailv[j];
    for (int m = s; m < e; ++m) {
      int t = bidx[b * TT + m];
      size_t base = (size_t)(b * TT + t) * VOCAB;
      out[base + c] = aj;
      if (c == 0) out[base + 256] = tl;
    }
  }
}

extern "C" void kernel_launch(void* const* d_in, const int* in_sizes, int n_in,
                              void* d_out, int out_size, void* d_ws, size_t ws_size,
                              hipStream_t stream) {
  (void)in_sizes; (void)n_in; (void)out_size; (void)ws_size;
  const int*   tokens     = (const int*)d_in[0];
  const float* embed      = (const float*)d_in[1];
  const float* pin_w      = (const float*)d_in[2];
  const float* pin_b      = (const float*)d_in[3];
  const float* pch_w      = (const float*)d_in[4];
  const float* pch_b      = (const float*)d_in[5];
  const float* depth_bias = (const float*)d_in[6];
  // d_in[7..10] = q_w,q_b,k_w,k_b: provably unused (uniform softmax)
  const float* v_w        = (const float*)d_in[11];
  const float* v_b        = (const float*)d_in[12];
  const float* o_w        = (const float*)d_in[13];
  const float* o_b        = (const float*)d_in[14];
  const float* level_gate = (const float*)d_in[15];
  const float* depth_gate = (const float*)d_in[16];
  const float* in_proj_w  = (const float*)d_in[17];
  const float* in_proj_b  = (const float*)d_in[18];
  const float* out_proj_w = (const float*)d_in[19];
  const float* out_proj_b = (const float*)d_in[20];
  const float* ln_g       = (const float*)d_in[21];
  const float* ln_b       = (const float*)d_in[22];
  const float* ic_gate    = (const float*)d_in[23];
  const float* gate_w     = (const float*)d_in[24];
  const float* gate_b     = (const float*)d_in[25];
  const float* ew1        = (const float*)d_in[26];
  const float* eb1        = (const float*)d_in[27];
  const float* ew2        = (const float*)d_in[28];
  const float* eb2        = (const float*)d_in[29];
  const float* hw1        = (const float*)d_in[30];
  const float* hb1        = (const float*)d_in[31];
  const float* hw2        = (const float*)d_in[32];
  const float* hb2        = (const float*)d_in[33];
  float* out = (float*)d_out;

  float* ws      = (float*)d_ws;
  int*   wflag   = (int*)ws;             // 1 int (memset to 0 each launch)
  float* rootA   = ws + 4096;            // 4096 floats
  float* root2   = ws + 8192;            // 4096 floats
  int*   bidx    = (int*)(ws + 43136);   // 16*2048 = 32768 ints
  int*   boff    = (int*)(ws + 75904);   // 16*258  =  4128 ints
  float* wsW     = ws + 131072;          // 4 x 256x256 fused W_l (1MB)
  float* wsb     = ws + 393216;          // 4 x 256 fused b_l

  hipMemsetAsync(wflag, 0, sizeof(int), stream);
  k_fractal<<<256, 1024, 0, stream>>>(tokens, embed, pin_w, pin_b, pch_w, pch_b,
                                      depth_bias, v_w, v_b, o_w, o_b, level_gate,
                                      depth_gate, in_proj_w, in_proj_b, out_proj_w,
                                      out_proj_b, ln_g, ln_b, ic_gate, ew1, ew2,
                                      hw1, hw2, rootA, root2, bidx, boff,
                                      wsW, wsb, wflag);
  k_moe<<<256, 256, 0, stream>>>(rootA, gate_w, gate_b, ew1, eb1,
                                 ew2, eb2, hw1, hw2, embed, root2);
  k_logits<<<dim3(VOCAB, 4), 256, 0, stream>>>(embed, root2, hw1, hb1, hw2, hb2,
                                               bidx, boff, out);
}

// Round 11
// 387.784 us; speedup vs baseline: 1.2752x; 1.2752x over previous
//
#include <hip/hip_runtime.h>
#include <hip/hip_bf16.h>
#include <math.h>

#define DIM    256
#define DEPTH  5
#define FANOUT 10
#define VOCAB  257
#define BB     16
#define TT     2048
#define NEXP   8
#define HID    512
#define TOPK   2
#define CAP    5   // ceil(16*2/8*1.1)

__device__ __forceinline__ float sigm(float x) { return 1.f / (1.f + expf(-x)); }

// 256x256 matvec partial: 1024 threads = 16 ksegs x 64 col-quads.
// Depth-8 float4 batches inside a KEPT loop (#pragma unroll 1): 2 latency
// exposures per matvec. R1-R3/R10 lesson: >8-deep per-thread batches at the
// 64-VGPR cap (1024-thread blocks) spill to scratch; 8-deep is the proven dose.
__device__ __forceinline__ void mv8x2(const float* sv, const float* __restrict__ W,
                                      int kseg, int cq, float red[16][DIM]) {
  const float* Wp = W + (size_t)kseg * 16 * DIM + cq * 4;
  float4 acc = {0.f, 0.f, 0.f, 0.f};
#pragma unroll 1
  for (int h = 0; h < 2; ++h) {
    float4 wv[8];
#pragma unroll
    for (int i = 0; i < 8; ++i)
      wv[i] = *(const float4*)(Wp + (size_t)(h * 8 + i) * DIM);
#pragma unroll
    for (int i = 0; i < 8; ++i) {
      float s = sv[kseg * 16 + h * 8 + i];
      acc.x = fmaf(s, wv[i].x, acc.x);
      acc.y = fmaf(s, wv[i].y, acc.y);
      acc.z = fmaf(s, wv[i].z, acc.z);
      acc.w = fmaf(s, wv[i].w, acc.w);
    }
    __builtin_amdgcn_sched_barrier(0);
  }
  *(float4*)&red[kseg][cq * 4] = acc;
}

__device__ __forceinline__ float sum16(const float red[16][DIM], int d) {
  float s = 0.f;
#pragma unroll
  for (int g = 0; g < 16; ++g) s += red[g][d];
  return s;
}

// ------ collapsed fractal + fused-weight precompute + root2 init --------------
// Grid = 256 blocks, role = bx&7 (XCD id):
//   xcd 0, slot 0..15  : 16 real chains (11 matvec units after v*pch fusion).
//   xcd 0, slot 16..31 : producers: W_l = v_w*diag(sigm(dg_l))*pch_w, b_l.
//                        R10 post-mortem: acc[16]+wv[16] spilled at the 64-VGPR
//                        cap (WRITE 3.5MB, producers ~270us). Now 2-pass x
//                        32-row with acc[8]+wv[8] (mv8x2's proven dose), vg
//                        aliased into red11 (no LDS growth). Warm o/pin/embed
//                        BEFORE producing, in_proj/out_proj after.
//   xcd 1, slot 0..15  : token-CSR build. slot 16..31: hw1/hw2/embed warm.
//   xcd >= 2           : warm ew1/ew2 during the chain (k_moe starts warm).
// Fusion arithmetic verified: R10 passed with absmax bit-identical.
__global__ void __launch_bounds__(1024) k_fractal(
    const int* __restrict__ tokens, const float* __restrict__ embed,
    const float* __restrict__ pin_w, const float* __restrict__ pin_b,
    const float* __restrict__ pch_w, const float* __restrict__ pch_b,
    const float* __restrict__ depth_bias,
    const float* __restrict__ v_w, const float* __restrict__ v_b,
    const float* __restrict__ o_w, const float* __restrict__ o_b,
    const float* __restrict__ level_gate, const float* __restrict__ depth_gate,
    const float* __restrict__ in_proj_w, const float* __restrict__ in_proj_b,
    const float* __restrict__ out_proj_w, const float* __restrict__ out_proj_b,
    const float* __restrict__ ln_g, const float* __restrict__ ln_b,
    const float* __restrict__ ic_gate,
    const float* __restrict__ ew1, const float* __restrict__ ew2,
    const float* __restrict__ hw1, const float* __restrict__ hw2,
    float* __restrict__ rootA, float* __restrict__ root2,
    int* __restrict__ bidx, int* __restrict__ boff,
    float* __restrict__ wsW, float* __restrict__ wsb,
    int* __restrict__ wflag) {
  int bx = blockIdx.x;
  int tid = threadIdx.x;
  int xcd = bx & 7, slot = bx >> 3;
  __shared__ int cnt[VOCAB];
  __shared__ float sv[DIM];
  __shared__ float basev[DIM];
  __shared__ float ym[DEPTH][DIM];
  __shared__ float q0v[DIM], kh[DEPTH][DIM], vh[DEPTH][DIM];
  __shared__ float red11[4][11][DIM];   // in_proj reduction; aliases red16 & vg
  __shared__ float zsv[DIM];
  __shared__ float aw[16];
  __shared__ float redl[8];
  __shared__ int offb[VOCAB + 1];
  __shared__ int woff[VOCAB];
  float (*red16)[DIM] = reinterpret_cast<float(*)[DIM]>(&red11[0][0][0]); // 16KB of 44KB

  if (xcd >= 2) {
    // ---- warm ew1/ew2 into this XCD's L2 during the chain (for k_moe) ----
    int wi = (xcd - 2) * 32 + slot;     // 0..191
    int r = wi % 128;
    const float* W = (r < 64) ? ew1 + (size_t)r * 16384
                              : ew2 + (size_t)(r - 64) * 16384;
    const float4* src = (const float4*)W + tid;
    float sx = 0.f, sy = 0.f, sz = 0.f, sw = 0.f;
#pragma unroll
    for (int k2 = 0; k2 < 4; ++k2) {
      float4 v = src[k2 * 1024];
      sx += v.x; sy += v.y; sz += v.z; sw += v.w;
    }
    asm volatile("" :: "v"(sx), "v"(sy), "v"(sz), "v"(sw));
    return;
  }
  if (xcd == 1) {
    if (slot < BB) {
      // ---- token CSR for batch b: off the chain's critical path ----
      int b = slot;
      for (int i = tid; i < VOCAB; i += 1024) cnt[i] = 0;
      __syncthreads();
      for (int t = tid; t < TT; t += 1024) atomicAdd(&cnt[tokens[b * TT + t]], 1);
      __syncthreads();
      if (tid == 0) {
        int a = 0;
        for (int v = 0; v < VOCAB; ++v) { offb[v] = a; a += cnt[v]; }
        offb[VOCAB] = a;              // == TT
      }
      __syncthreads();
      if (tid <= VOCAB) boff[b * (VOCAB + 1) + tid] = offb[tid];
      if (tid < VOCAB) woff[tid] = offb[tid];
      __syncthreads();
      for (int t = tid; t < TT; t += 1024) {
        int tok = tokens[b * TT + t];
        int p = atomicAdd(&woff[tok], 1);
        bidx[b * TT + p] = t;         // bucket order arbitrary; output order-invariant
      }
    } else {
      // warm hw1/hw2/embed for k_logits (L3-level benefit)
      int r = (slot - BB) % 12;
      const float* W;
      if (r < 4)       W = hw1   + (size_t)r * 16384;
      else if (r < 8)  W = hw2   + (size_t)(r - 4) * 16384;
      else             W = embed + (size_t)(r - 8) * 16384;
      const float4* src = (const float4*)W + tid;
      float sx = 0.f, sy = 0.f, sz = 0.f, sw = 0.f;
#pragma unroll
      for (int k2 = 0; k2 < 4; ++k2) {
        float4 v = src[k2 * 1024];
        sx += v.x; sy += v.y; sz += v.z; sw += v.w;
      }
      asm volatile("" :: "v"(sx), "v"(sy), "v"(sz), "v"(sw));
    }
    return;
  }
  if (slot >= BB) {
    // ---- producer: W_l (64 rows, 2 passes of 32) + b_l; same XCD as chains --
    int p = slot - BB;                 // 0..15
    int l = p & 3, rowbase = (p >> 2) * 64;
    int j = tid & 255, iq = tid >> 8;  // iq 0..3 -> 8 rows each per pass
    // phase A: warm one early-needed region while chains do histogram/context
    if (p < 12) {
      const float* W;
      if (p < 4)      W = o_w   + (size_t)p * 16384;
      else if (p < 8) W = pin_w + (size_t)(p - 4) * 16384;
      else            W = embed + (size_t)(p - 8) * 16384;
      const float4* src = (const float4*)W + tid;
      float sx = 0.f, sy = 0.f, sz = 0.f, sw = 0.f;
#pragma unroll
      for (int k2 = 0; k2 < 4; ++k2) {
        float4 v = src[k2 * 1024];
        sx += v.x; sy += v.y; sz += v.z; sw += v.w;
      }
      asm volatile("" :: "v"(sx), "v"(sy), "v"(sz), "v"(sw));
    }
    if (tid < DIM) {
      float g = sigm(depth_gate[l * DIM + tid]);
      basev[tid] = g;
      sv[tid] = v_b[tid] * g;
    }
    float* vg = &red11[0][0][0];       // [32][DIM] alias (32KB of 44KB)
    float bacc = 0.f;
#pragma unroll 1
    for (int pass = 0; pass < 2; ++pass) {
      int rb = rowbase + pass * 32;
      __syncthreads();                 // vg free / gl+sv ready
      for (int idx = tid; idx < 32 * 64; idx += 1024) {   // float4 units
        int i = idx >> 6, c4 = idx & 63;
        float4 v = *(const float4*)&v_w[(size_t)(rb + i) * DIM + c4 * 4];
        v.x *= basev[c4 * 4];     v.y *= basev[c4 * 4 + 1];
        v.z *= basev[c4 * 4 + 2]; v.w *= basev[c4 * 4 + 3];
        *(float4*)&vg[i * DIM + c4 * 4] = v;
      }
      __syncthreads();
      float acc[8];
#pragma unroll
      for (int r = 0; r < 8; ++r) acc[r] = 0.f;
#pragma unroll 1
      for (int kb = 0; kb < DIM; kb += 8) {
        float wv[8];
#pragma unroll
        for (int i = 0; i < 8; ++i) wv[i] = pch_w[(size_t)(kb + i) * DIM + j];
#pragma unroll
        for (int i = 0; i < 8; ++i) {
          float w = wv[i];
          int k = kb + i;
#pragma unroll
          for (int r = 0; r < 8; ++r)
            acc[r] = fmaf(vg[(iq * 8 + r) * DIM + k], w, acc[r]); // LDS broadcast
          if (pass == 0) bacc = fmaf(sv[k], w, bacc);
        }
        __builtin_amdgcn_sched_barrier(0);
      }
      float* Wl = wsW + (size_t)l * 65536;
#pragma unroll
      for (int r = 0; r < 8; ++r)
        Wl[(size_t)(rb + iq * 8 + r) * DIM + j] = acc[r];
    }
    if (iq == 0 && (p >> 2) == 0)
      wsb[l * DIM + j] = bacc + pch_b[j];
    __threadfence();
    __syncthreads();
    if (tid == 0) atomicAdd(wflag, 1);
    // phase B: warm in_proj/out_proj (needed ~20us in)
    {
      int r = p;
      const float* W = (r < 12) ? in_proj_w + (size_t)r * 16384
                                : out_proj_w + (size_t)(r - 12) * 16384;
      const float4* src = (const float4*)W + tid;
      float sx = 0.f, sy = 0.f, sz = 0.f, sw = 0.f;
#pragma unroll
      for (int k2 = 0; k2 < 4; ++k2) {
        float4 v = src[k2 * 1024];
        sx += v.x; sy += v.y; sz += v.z; sw += v.w;
      }
      asm volatile("" :: "v"(sx), "v"(sy), "v"(sz), "v"(sw));
    }
    return;
  }

  int b = slot;
  int d = tid & 255;
  int ks = tid >> 8;       // 0..3 (consumer / in_proj layout)
  int k0 = ks * 64;
  int kseg = tid >> 6;     // 0..15 (mv8x2 layout)
  int cq = tid & 63;

  // ---- context = (histogram @ embed) / T, branch-free ----
  for (int i = tid; i < VOCAB; i += 1024) cnt[i] = 0;
  __syncthreads();
  for (int t = tid; t < TT; t += 1024) atomicAdd(&cnt[tokens[b * TT + t]], 1);
  __syncthreads();
  {
    const float* Ep = embed + (size_t)kseg * 16 * DIM + cq * 4;
    float4 acc = {0.f, 0.f, 0.f, 0.f};
#pragma unroll 1
    for (int h = 0; h < 2; ++h) {
      float4 ev[8];
#pragma unroll
      for (int i = 0; i < 8; ++i)
        ev[i] = *(const float4*)(Ep + (size_t)(h * 8 + i) * DIM);
#pragma unroll
      for (int i = 0; i < 8; ++i) {
        float cv = (float)cnt[kseg * 16 + h * 8 + i];
        acc.x = fmaf(cv, ev[i].x, acc.x);
        acc.y = fmaf(cv, ev[i].y, acc.y);
        acc.z = fmaf(cv, ev[i].z, acc.z);
        acc.w = fmaf(cv, ev[i].w, acc.w);
      }
      __builtin_amdgcn_sched_barrier(0);
    }
    *(float4*)&red16[kseg][cq * 4] = acc;
  }
  __syncthreads();
  if (ks == 0) {
    float s = sum16(red16, d);
    s = fmaf((float)cnt[256], embed[(size_t)256 * DIM + d], s);
    sv[d] = s * (1.0f / (float)TT);
  }
  __syncthreads();

  mv8x2(sv, pin_w, kseg, cq, red16);
  __syncthreads();
  if (ks == 0) {
    float base = sum16(red16, d) + pin_b[d];
    basev[d] = base;
    float u = (base + depth_bias[4 * DIM + d] + pch_b[d]) * sigm(level_gate[4]);
    sv[d] = fmaxf(u, 0.f);
  }
  __syncthreads();
  mv8x2(sv, o_w, kseg, cq, red16);
  __syncthreads();
  if (ks == 0) {
    float y = sum16(red16, d) + o_b[d];
    ym[4][d] = y;
    sv[d] = y;
  }
  __syncthreads();
  // gate on producers (they finish ~8us in; we arrive ~11us -> ~0 wait)
  if (tid == 0) {
    while (__hip_atomic_load(wflag, __ATOMIC_ACQUIRE, __HIP_MEMORY_SCOPE_AGENT) < 16) {}
  }
  __syncthreads();
  for (int l = 3; l >= 0; --l) {
    mv8x2(sv, wsW + (size_t)l * 65536, kseg, cq, red16);   // fused v*g*pch
    __syncthreads();
    if (ks == 0) {
      float t = sum16(red16, d) + wsb[l * DIM + d];
      float u = (basev[d] + depth_bias[l * DIM + d] + t) * sigm(level_gate[l]);
      sv[d] = fmaxf(u, 0.f);
    }
    __syncthreads();
    mv8x2(sv, o_w, kseg, cq, red16);
    __syncthreads();
    if (ks == 0) {
      float y = sum16(red16, d) + o_b[d];
      ym[l][d] = y;
      sv[d] = y;
    }
    __syncthreads();
  }
  // ---- in_proj, ALL levels in ONE pass over the weights (8-deep batches) ----
  {
    float aq = 0.f;
    float ak0 = 0.f, ak1 = 0.f, ak2 = 0.f, ak3 = 0.f, ak4 = 0.f;
    float av0 = 0.f, av1 = 0.f, av2 = 0.f, av3 = 0.f, av4 = 0.f;
#pragma unroll
    for (int h = 0; h < 8; ++h) {
      int kb = k0 + h * 8;
      float wq[8], wk[8], wv8[8];
#pragma unroll
      for (int i = 0; i < 8; ++i) {
        const float* wrow = in_proj_w + (size_t)(kb + i) * 768;
        wq[i] = wrow[d]; wk[i] = wrow[256 + d]; wv8[i] = wrow[512 + d];
      }
#pragma unroll
      for (int i = 0; i < 8; ++i) {
        float z0 = ym[0][kb + i];
        aq  = fmaf(z0, wq[i], aq);
        ak0 = fmaf(z0, wk[i], ak0);
        av0 = fmaf(z0, wv8[i], av0);
        float z1 = ym[1][kb + i];
        ak1 = fmaf(z1, wk[i], ak1);
        av1 = fmaf(z1, wv8[i], av1);
        float z2 = ym[2][kb + i];
        ak2 = fmaf(z2, wk[i], ak2);
        av2 = fmaf(z2, wv8[i], av2);
        float z3 = ym[3][kb + i];
        ak3 = fmaf(z3, wk[i], ak3);
        av3 = fmaf(z3, wv8[i], av3);
        float z4 = ym[4][kb + i];
        ak4 = fmaf(z4, wk[i], ak4);
        av4 = fmaf(z4, wv8[i], av4);
      }
    }
    red11[ks][0][d] = ak0; red11[ks][1][d] = ak1; red11[ks][2][d] = ak2;
    red11[ks][3][d] = ak3; red11[ks][4][d] = ak4;
    red11[ks][5][d] = av0; red11[ks][6][d] = av1; red11[ks][7][d] = av2;
    red11[ks][8][d] = av3; red11[ks][9][d] = av4;
    red11[ks][10][d] = aq;
  }
  __syncthreads();
  for (int idx = tid; idx < 11 * DIM; idx += 1024) {
    int c = idx >> 8, dd = idx & 255;
    float sum = red11[0][c][dd] + red11[1][c][dd] + red11[2][c][dd] + red11[3][c][dd];
    if (c < 5)       kh[c][dd]     = sum + in_proj_b[256 + dd];
    else if (c < 10) vh[c - 5][dd] = sum + in_proj_b[512 + dd];
    else             q0v[dd]       = sum + in_proj_b[dd];
  }
  __syncthreads();
  {
    int wid = tid >> 6;
    if (wid < 10) {
      int h = wid / 5, l = wid - h * 5;
      int lane = tid & 63;
      float s = q0v[h * 128 + lane] * kh[l][h * 128 + lane];
      s = fmaf(q0v[h * 128 + 64 + lane], kh[l][h * 128 + 64 + lane], s);
      for (int o = 32; o > 0; o >>= 1) s += __shfl_down(s, o, 64);
      if (lane == 0) aw[wid] = s * 0.08838834764831845f;  // 1/sqrt(128)
    }
  }
  __syncthreads();
  if (tid < 2) {
    float m = aw[tid * 5];
    for (int l = 1; l < 5; ++l) m = fmaxf(m, aw[tid * 5 + l]);
    float e[5], ssum = 0.f;
    for (int l = 0; l < 5; ++l) { e[l] = expf(aw[tid * 5 + l] - m); ssum += e[l]; }
    for (int l = 0; l < 5; ++l) aw[tid * 5 + l] = e[l] / ssum;
  }
  __syncthreads();
  if (ks == 0) {
    int h = d >> 7;
    float z2 = 0.f;
    for (int l = 0; l < 5; ++l) z2 = fmaf(aw[h * 5 + l], vh[l][d], z2);
    sv[d] = z2;
  }
  __syncthreads();
  mv8x2(sv, out_proj_w, kseg, cq, red16);
  __syncthreads();
  if (ks == 0) {
    float z2p = sum16(red16, d) + out_proj_b[d];
    zsv[d] = ym[0][d] + z2p;
  }
  __syncthreads();
  float zs = 0.f, df = 0.f, mu = 0.f;
  if (tid < 256) {
    zs = zsv[tid];
    float v = zs;
    for (int o = 32; o > 0; o >>= 1) v += __shfl_down(v, o, 64);
    if ((tid & 63) == 0) redl[tid >> 6] = v;
  }
  __syncthreads();
  if (tid < 256) {
    mu = (redl[0] + redl[1] + redl[2] + redl[3]) * (1.f / 256.f);
    df = zs - mu;
  }
  __syncthreads();
  if (tid < 256) {
    float v = df * df;
    for (int o = 32; o > 0; o >>= 1) v += __shfl_down(v, o, 64);
    if ((tid & 63) == 0) redl[tid >> 6] = v;
  }
  __syncthreads();
  if (tid < 256) {
    float var = (redl[0] + redl[1] + redl[2] + redl[3]) * (1.f / 256.f);
    float zn = df / sqrtf(var + 1e-5f) * ln_g[tid] + ln_b[tid];
    float r = ym[0][tid] + sigm(ic_gate[0]) * zn;
    rootA[b * DIM + tid] = r;
    root2[b * DIM + tid] = r;   // experts atomically add on top
  }
}

// ---- fused MoE: gating + GEMM1 + partial-GEMM2 + combine -------------------
// Blocks 0..63 = 8 experts x 8 tiles of 64 HID cols. Blocks 64..255 = warmers
// for hw1/hw2/embed (ew1/ew2 already warmed by k_fractal's xcd>=2 blocks).
__global__ void __launch_bounds__(256) k_moe(
    const float* __restrict__ rootA,
    const float* __restrict__ gate_w, const float* __restrict__ gate_b,
    const float* __restrict__ ew1, const float* __restrict__ eb1,
    const float* __restrict__ ew2, const float* __restrict__ eb2,
    const float* __restrict__ hw1, const float* __restrict__ hw2,
    const float* __restrict__ embed,
    float* __restrict__ root2) {
  int bx = blockIdx.x;
  int tid = threadIdx.x;
  if (bx >= 64) {
    int r = (bx - 64) % 12;
    const float* W;
    if (r < 4)       W = hw1   + (size_t)r * 16384;
    else if (r < 8)  W = hw2   + (size_t)(r - 4) * 16384;
    else             W = embed + (size_t)(r - 8) * 16384;
    const float4* src = (const float4*)W + tid;
    float sx = 0.f, sy = 0.f, sz = 0.f, sw = 0.f;
#pragma unroll 4
    for (int i = 0; i < 16; ++i) {
      float4 v = src[i * 256];
      sx += v.x; sy += v.y; sz += v.z; sw += v.w;
    }
    asm volatile("" :: "v"(sx), "v"(sy), "v"(sz), "v"(sw));
    return;
  }
  int e = bx >> 3, jt = bx & 7, j0 = jt * 64;
  int w = tid >> 6, lane = tid & 63;
  __shared__ float rlds[BB * DIM];      // 16KB rootA copy
  __shared__ float gwlds[DIM * NEXP];   // 8KB gate_w copy
  __shared__ float xin[CAP][DIM];
  __shared__ float red[CAP][4][64];
  __shared__ float hloc[CAP][64];
  __shared__ float sc[BB * NEXP];
  __shared__ float gs[BB * TOPK];
  __shared__ int gidx[BB * TOPK];
  __shared__ int stok[CAP];
  __shared__ float swt[CAP];
  for (int idx = tid; idx < BB * DIM / 4; idx += 256)
    *(float4*)&rlds[idx * 4] = *(const float4*)&rootA[idx * 4];
  for (int idx = tid; idx < DIM * NEXP / 4; idx += 256)
    *(float4*)&gwlds[idx * 4] = *(const float4*)&gate_w[idx * 4];
  __syncthreads();
  if (tid < BB * NEXP) {
    int b = tid >> 3, ep = tid & 7;
    float chunk[8];
#pragma unroll
    for (int g = 0; g < 8; ++g) {
      float acc = 0.f;
#pragma unroll 8
      for (int i = 0; i < 32; ++i) {
        int k = g * 32 + i;
        acc = fmaf(rlds[b * DIM + k], gwlds[k * NEXP + ep], acc);
      }
      chunk[g] = acc;
    }
    float s = gate_b[ep];
#pragma unroll
    for (int g = 0; g < 8; ++g) s += chunk[g];
    sc[tid] = s;
  }
  __syncthreads();
  if (tid < BB) {  // top-2 + softmax per batch (identical order to old k_gate)
    int bb = tid;
    int i0 = 0; float v0 = sc[bb * 8 + 0];
    for (int ee = 1; ee < 8; ++ee) { float v = sc[bb * 8 + ee]; if (v > v0) { v0 = v; i0 = ee; } }
    int i1 = -1; float v1 = -1e30f;
    for (int ee = 0; ee < 8; ++ee) {
      if (ee == i0) continue;
      float v = sc[bb * 8 + ee];
      if (v > v1) { v1 = v; i1 = ee; }
    }
    float e1v = expf(v1 - v0);
    float s = 1.f + e1v;
    gs[bb * 2 + 0] = 1.f / s;  gidx[bb * 2 + 0] = i0;
    gs[bb * 2 + 1] = e1v / s;  gidx[bb * 2 + 1] = i1;
  }
  __syncthreads();
  if (tid == 0) {  // top-CAP for own expert: bitmask, value desc / index asc
    unsigned used = 0u;
    for (int s = 0; s < CAP; ++s) {
      int bi = 0; float bv = -1e30f;
      for (int i = 0; i < 32; ++i) {
        if (used & (1u << i)) continue;
        float v = (gidx[i] == e) ? gs[i] : -1.0f;
        if (v > bv) { bv = v; bi = i; }
      }
      used |= (1u << bi);
      stok[s] = bi >> 1;
      swt[s] = bv > 0.f ? bv : 0.f;
    }
  }
  __syncthreads();
  for (int idx = tid; idx < CAP * DIM; idx += 256) {
    int s = idx >> 8, k = idx & 255;
    xin[s][k] = rlds[stok[s] * DIM + k];
  }
  __syncthreads();
  // GEMM1: this block's 64 HID cols (identical order to old k_expert1)
  {
    float a0 = 0.f, a1 = 0.f, a2 = 0.f, a3 = 0.f, a4 = 0.f;
    const float* W = ew1 + (size_t)e * DIM * HID + j0 + lane;  // row k -> +k*HID
    int kbase = w * 64;
#pragma unroll
    for (int h = 0; h < 8; ++h) {
      float wv[8];
#pragma unroll
      for (int i = 0; i < 8; ++i) wv[i] = W[(size_t)(kbase + h * 8 + i) * HID];
#pragma unroll
      for (int i = 0; i < 8; ++i) {
        int k = kbase + h * 8 + i;
        a0 = fmaf(xin[0][k], wv[i], a0);
        a1 = fmaf(xin[1][k], wv[i], a1);
        a2 = fmaf(xin[2][k], wv[i], a2);
        a3 = fmaf(xin[3][k], wv[i], a3);
        a4 = fmaf(xin[4][k], wv[i], a4);
      }
    }
    red[0][w][lane] = a0; red[1][w][lane] = a1; red[2][w][lane] = a2;
    red[3][w][lane] = a3; red[4][w][lane] = a4;
  }
  __syncthreads();
  for (int idx = tid; idx < CAP * 64; idx += 256) {
    int s = idx >> 6, j = idx & 63;
    float sum = red[s][0][j] + red[s][1][j] + red[s][2][j] + red[s][3][j]
              + eb1[e * HID + j0 + j];
    hloc[s][j] = fmaxf(sum, 0.f);
  }
  __syncthreads();
  // partial GEMM2: K = this block's 64 hid cols, d = tid (0..255)
  {
    int d = tid;
    float a0 = 0.f, a1 = 0.f, a2 = 0.f, a3 = 0.f, a4 = 0.f;
    const float* W2 = ew2 + (size_t)e * HID * DIM + (size_t)j0 * DIM + d;
#pragma unroll
    for (int h = 0; h < 8; ++h) {
      float wv[8];
#pragma unroll
      for (int i = 0; i < 8; ++i) wv[i] = W2[(size_t)(h * 8 + i) * DIM];
#pragma unroll
      for (int i = 0; i < 8; ++i) {
        int j = h * 8 + i;
        a0 = fmaf(hloc[0][j], wv[i], a0);
        a1 = fmaf(hloc[1][j], wv[i], a1);
        a2 = fmaf(hloc[2][j], wv[i], a2);
        a3 = fmaf(hloc[3][j], wv[i], a3);
        a4 = fmaf(hloc[4][j], wv[i], a4);
      }
    }
    float bias = (jt == 0) ? eb2[e * DIM + d] : 0.f;
#pragma unroll
    for (int s = 0; s < CAP; ++s) {
      float as = (s == 0) ? a0 : (s == 1) ? a1 : (s == 2) ? a2 : (s == 3) ? a3 : a4;
      float wgt = swt[s];
      if (wgt > 0.f)
        atomicAdd(&root2[stok[s] * DIM + d], (as + bias) * wgt);
    }
  }
}

// ---- logits + fused scatter: grid (257 tokens x 4 rowgroups) x 256 threads --
// R5-proven shape: 1028 blocks keeps the machine latency-tolerant; weights
// (520KB) are L2-resident so redundant reads are cheap.
__global__ void __launch_bounds__(256) k_logits(
    const float* __restrict__ embed, const float* __restrict__ root2,
    const float* __restrict__ hw1, const float* __restrict__ hb1,
    const float* __restrict__ hw2, const float* __restrict__ hb2,
    const int* __restrict__ bidx, const int* __restrict__ boff,
    float* __restrict__ out) {
  int tok = blockIdx.x, r0 = blockIdx.y * 4;
  int c = threadIdx.x;
  __shared__ float hrow[4][DIM];
  __shared__ float hid[4][DIM];
  __shared__ float tailred[4][17];
  __shared__ float tailv[4];
  {
    float ev = embed[(size_t)tok * DIM + c];
#pragma unroll
    for (int j = 0; j < 4; ++j) hrow[j][c] = ev + root2[(size_t)(r0 + j) * DIM + c];
  }
  __syncthreads();
  // GEMM1: col c over K=256, 4 rows
  {
    float a0 = hb1[c], a1 = a0, a2 = a0, a3 = a0;
    for (int kb = 0; kb < DIM; kb += 8) {
      float wv[8];
#pragma unroll
      for (int i = 0; i < 8; ++i) wv[i] = hw1[(size_t)(kb + i) * DIM + c];
#pragma unroll
      for (int i = 0; i < 8; ++i) {
        int k = kb + i;
        a0 = fmaf(hrow[0][k], wv[i], a0);
        a1 = fmaf(hrow[1][k], wv[i], a1);
        a2 = fmaf(hrow[2][k], wv[i], a2);
        a3 = fmaf(hrow[3][k], wv[i], a3);
      }
    }
    hid[0][c] = fmaxf(a0, 0.f); hid[1][c] = fmaxf(a1, 0.f);
    hid[2][c] = fmaxf(a2, 0.f); hid[3][c] = fmaxf(a3, 0.f);
  }
  __syncthreads();
  // GEMM2: cols 0..255 into registers
  float a0, a1, a2, a3;
  {
    a0 = hb2[c]; a1 = a0; a2 = a0; a3 = a0;
    for (int kb = 0; kb < DIM; kb += 8) {
      float wv[8];
#pragma unroll
      for (int i = 0; i < 8; ++i) wv[i] = hw2[(size_t)(kb + i) * VOCAB + c];
#pragma unroll
      for (int i = 0; i < 8; ++i) {
        int k = kb + i;
        a0 = fmaf(hid[0][k], wv[i], a0);
        a1 = fmaf(hid[1][k], wv[i], a1);
        a2 = fmaf(hid[2][k], wv[i], a2);
        a3 = fmaf(hid[3][k], wv[i], a3);
      }
    }
  }
  // tail column 256: 16-way K-split across first 64 threads
  if (c < 64) {
    int r = c >> 4, seg = c & 15;
    float sum = 0.f;
#pragma unroll 4
    for (int i = 0; i < 16; ++i) {
      int k = seg * 16 + i;
      sum = fmaf(hid[r][k], hw2[(size_t)k * VOCAB + 256], sum);
    }
    tailred[r][seg] = sum;
  }
  __syncthreads();
  if (c < 4) {
    float a = hb2[256];
#pragma unroll
    for (int s = 0; s < 16; ++s) a += tailred[c][s];
    tailv[c] = a;
  }
  __syncthreads();
  // fused scatter: write this row to every matching t (coalesced 1KB rows)
#pragma unroll
  for (int j = 0; j < 4; ++j) {
    int b = r0 + j;
    int s = boff[b * (VOCAB + 1) + tok];
    int e = boff[b * (VOCAB + 1) + tok + 1];
    float aj = (j == 0) ? a0 : (j == 1) ? a1 : (j == 2) ? a2 : a3;
    float tl = tailv[j];
    for (int m = s; m < e; ++m) {
      int t = bidx[b * TT + m];
      size_t base = (size_t)(b * TT + t) * VOCAB;
      out[base + c] = aj;
      if (c == 0) out[base + 256] = tl;
    }
  }
}

extern "C" void kernel_launch(void* const* d_in, const int* in_sizes, int n_in,
                              void* d_out, int out_size, void* d_ws, size_t ws_size,
                              hipStream_t stream) {
  (void)in_sizes; (void)n_in; (void)out_size; (void)ws_size;
  const int*   tokens     = (const int*)d_in[0];
  const float* embed      = (const float*)d_in[1];
  const float* pin_w      = (const float*)d_in[2];
  const float* pin_b      = (const float*)d_in[3];
  const float* pch_w      = (const float*)d_in[4];
  const float* pch_b      = (const float*)d_in[5];
  const float* depth_bias = (const float*)d_in[6];
  // d_in[7..10] = q_w,q_b,k_w,k_b: provably unused (uniform softmax)
  const float* v_w        = (const float*)d_in[11];
  const float* v_b        = (const float*)d_in[12];
  const float* o_w        = (const float*)d_in[13];
  const float* o_b        = (const float*)d_in[14];
  const float* level_gate = (const float*)d_in[15];
  const float* depth_gate = (const float*)d_in[16];
  const float* in_proj_w  = (const float*)d_in[17];
  const float* in_proj_b  = (const float*)d_in[18];
  const float* out_proj_w = (const float*)d_in[19];
  const float* out_proj_b = (const float*)d_in[20];
  const float* ln_g       = (const float*)d_in[21];
  const float* ln_b       = (const float*)d_in[22];
  const float* ic_gate    = (const float*)d_in[23];
  const float* gate_w     = (const float*)d_in[24];
  const float* gate_b     = (const float*)d_in[25];
  const float* ew1        = (const float*)d_in[26];
  const float* eb1        = (const float*)d_in[27];
  const float* ew2        = (const float*)d_in[28];
  const float* eb2        = (const float*)d_in[29];
  const float* hw1        = (const float*)d_in[30];
  const float* hb1        = (const float*)d_in[31];
  const float* hw2        = (const float*)d_in[32];
  const float* hb2        = (const float*)d_in[33];
  float* out = (float*)d_out;

  float* ws      = (float*)d_ws;
  int*   wflag   = (int*)ws;             // 1 int (memset to 0 each launch)
  float* rootA   = ws + 4096;            // 4096 floats
  float* root2   = ws + 8192;            // 4096 floats
  int*   bidx    = (int*)(ws + 43136);   // 16*2048 = 32768 ints
  int*   boff    = (int*)(ws + 75904);   // 16*258  =  4128 ints
  float* wsW     = ws + 131072;          // 4 x 256x256 fused W_l (1MB)
  float* wsb     = ws + 393216;          // 4 x 256 fused b_l

  hipMemsetAsync(wflag, 0, sizeof(int), stream);
  k_fractal<<<256, 1024, 0, stream>>>(tokens, embed, pin_w, pin_b, pch_w, pch_b,
                                      depth_bias, v_w, v_b, o_w, o_b, level_gate,
                                      depth_gate, in_proj_w, in_proj_b, out_proj_w,
                                      out_proj_b, ln_g, ln_b, ic_gate, ew1, ew2,
                                      hw1, hw2, rootA, root2, bidx, boff,
                                      wsW, wsb, wflag);
  k_moe<<<256, 256, 0, stream>>>(rootA, gate_w, gate_b, ew1, eb1,
                                 ew2, eb2, hw1, hw2, embed, root2);
  k_logits<<<dim3(VOCAB, 4), 256, 0, stream>>>(embed, root2, hw1, hb1, hw2, hb2,
                                               bidx, boff, out);
}

// Round 12
// 229.654 us; speedup vs baseline: 2.1533x; 1.6886x over previous
//
#include <hip/hip_runtime.h>
#include <hip/hip_bf16.h>
#include <math.h>

#define DIM    256
#define DEPTH  5
#define FANOUT 10
#define VOCAB  257
#define BB     16
#define TT     2048
#define NEXP   8
#define HID    512
#define TOPK   2
#define CAP    5   // ceil(16*2/8*1.1)

__device__ __forceinline__ float sigm(float x) { return 1.f / (1.f + expf(-x)); }

// 256x256 matvec partial: 1024 threads = 16 ksegs x 64 col-quads.
// Depth-8 float4 batches inside a KEPT loop (#pragma unroll 1): 2 latency
// exposures per matvec. R1-R3/R10 lesson: fully-unrolled forms get ALL loads
// hoisted and spill at the 64-VGPR cap; only a real loop boundary stops it.
__device__ __forceinline__ void mv8x2(const float* sv, const float* __restrict__ W,
                                      int kseg, int cq, float red[16][DIM]) {
  const float* Wp = W + (size_t)kseg * 16 * DIM + cq * 4;
  float4 acc = {0.f, 0.f, 0.f, 0.f};
#pragma unroll 1
  for (int h = 0; h < 2; ++h) {
    float4 wv[8];
#pragma unroll
    for (int i = 0; i < 8; ++i)
      wv[i] = *(const float4*)(Wp + (size_t)(h * 8 + i) * DIM);
#pragma unroll
    for (int i = 0; i < 8; ++i) {
      float s = sv[kseg * 16 + h * 8 + i];
      acc.x = fmaf(s, wv[i].x, acc.x);
      acc.y = fmaf(s, wv[i].y, acc.y);
      acc.z = fmaf(s, wv[i].z, acc.z);
      acc.w = fmaf(s, wv[i].w, acc.w);
    }
    __builtin_amdgcn_sched_barrier(0);
  }
  *(float4*)&red[kseg][cq * 4] = acc;
}

__device__ __forceinline__ float sum16(const float red[16][DIM], int d) {
  float s = 0.f;
#pragma unroll
  for (int g = 0; g < 16; ++g) s += red[g][d];
  return s;
}

// ------ collapsed fractal + context + root2 init ------------------------------
// R9-verified configuration (best: 230.6us total, k_fractal 52us, FETCH 1.3MB).
// R10/R11 (v*pch producer fusion) both regressed (spill; then unexplained 4x
// producer slowdown) -> reverted per failure-read.
// Grid = 256 blocks, role = bx&7 (XCD id, round-robin block->XCD mapping):
//   xcd 0, slot 0..15  : the 16 real per-batch chains -> ALL ON ONE XCD, so
//                        only ONE private L2 holds the 2.4MB weight set.
//   xcd 0, slot 16..31 : warmers streaming the 37x64KB weight regions into
//                        XCD0's L2 while real blocks do the histogram phase.
//   xcd 1, slot 0..15  : token-CSR build (independent of the chain).
//   everything else    : exit.
__global__ void __launch_bounds__(1024) k_fractal(
    const int* __restrict__ tokens, const float* __restrict__ embed,
    const float* __restrict__ pin_w, const float* __restrict__ pin_b,
    const float* __restrict__ pch_w, const float* __restrict__ pch_b,
    const float* __restrict__ depth_bias,
    const float* __restrict__ v_w, const float* __restrict__ v_b,
    const float* __restrict__ o_w, const float* __restrict__ o_b,
    const float* __restrict__ level_gate, const float* __restrict__ depth_gate,
    const float* __restrict__ in_proj_w, const float* __restrict__ in_proj_b,
    const float* __restrict__ out_proj_w, const float* __restrict__ out_proj_b,
    const float* __restrict__ ln_g, const float* __restrict__ ln_b,
    const float* __restrict__ ic_gate,
    float* __restrict__ rootA, float* __restrict__ root2,
    int* __restrict__ bidx, int* __restrict__ boff) {
  int bx = blockIdx.x;
  int tid = threadIdx.x;
  int xcd = bx & 7, slot = bx >> 3;
  __shared__ int cnt[VOCAB];
  __shared__ float sv[DIM];
  __shared__ float basev[DIM];
  __shared__ float ym[DEPTH][DIM];
  __shared__ float q0v[DIM], kh[DEPTH][DIM], vh[DEPTH][DIM];
  __shared__ float red11[4][11][DIM];   // in_proj reduction; also aliases red16
  __shared__ float zsv[DIM];
  __shared__ float aw[16];
  __shared__ float redl[8];
  __shared__ int offb[VOCAB + 1];
  __shared__ int woff[VOCAB];
  float (*red16)[DIM] = reinterpret_cast<float(*)[DIM]>(&red11[0][0][0]); // 16KB of 44KB

  if (xcd == 1) {
    if (slot < BB) {
      // ---- token CSR for batch b: off the chain's critical path ----
      int b = slot;
      for (int i = tid; i < VOCAB; i += 1024) cnt[i] = 0;
      __syncthreads();
      for (int t = tid; t < TT; t += 1024) atomicAdd(&cnt[tokens[b * TT + t]], 1);
      __syncthreads();
      if (tid == 0) {
        int a = 0;
        for (int v = 0; v < VOCAB; ++v) { offb[v] = a; a += cnt[v]; }
        offb[VOCAB] = a;              // == TT
      }
      __syncthreads();
      if (tid <= VOCAB) boff[b * (VOCAB + 1) + tid] = offb[tid];
      if (tid < VOCAB) woff[tid] = offb[tid];
      __syncthreads();
      for (int t = tid; t < TT; t += 1024) {
        int tok = tokens[b * TT + t];
        int p = atomicAdd(&woff[tok], 1);
        bidx[b * TT + p] = t;         // bucket order arbitrary; output order-invariant
      }
    }
    return;
  }
  if (xcd != 0) return;
  if (slot >= BB) {
    // ---- warmer: 3 of the 37 64KB weight regions into XCD0's L2 ----
    int w = slot - BB;                // 0..15
    float sx = 0.f, sy = 0.f, sz = 0.f, sw = 0.f;
#pragma unroll 1
    for (int q = 0; q < 3; ++q) {
      int r = w * 3 + q;
      if (r >= 37) break;
      const float* W; int n = 16384;
      if (r < 4)       W = pin_w      + (size_t)r * 16384;
      else if (r < 8)  W = pch_w      + (size_t)(r - 4) * 16384;
      else if (r < 12) W = v_w        + (size_t)(r - 8) * 16384;
      else if (r < 16) W = o_w        + (size_t)(r - 12) * 16384;
      else if (r < 20) W = out_proj_w + (size_t)(r - 16) * 16384;
      else if (r < 32) W = in_proj_w  + (size_t)(r - 20) * 16384;
      else { W = embed + (size_t)(r - 32) * 16384; n = 65792 - (r - 32) * 16384;
             if (n > 16384) n = 16384; }
      const float4* src = (const float4*)W + tid;
#pragma unroll
      for (int k = 0; k < 4; ++k) {
        int p = tid * 4 + k * 4096;
        if (p + 4 <= n) {
          float4 v = src[k * 1024];
          sx += v.x; sy += v.y; sz += v.z; sw += v.w;
        }
      }
    }
    asm volatile("" :: "v"(sx), "v"(sy), "v"(sz), "v"(sw));
    return;
  }

  int b = slot;
  int d = tid & 255;
  int ks = tid >> 8;       // 0..3 (consumer / in_proj layout)
  int k0 = ks * 64;
  int kseg = tid >> 6;     // 0..15 (mv8x2 layout)
  int cq = tid & 63;

  // ---- context = (histogram @ embed) / T, branch-free ----
  for (int i = tid; i < VOCAB; i += 1024) cnt[i] = 0;
  __syncthreads();
  for (int t = tid; t < TT; t += 1024) atomicAdd(&cnt[tokens[b * TT + t]], 1);
  __syncthreads();
  {
    const float* Ep = embed + (size_t)kseg * 16 * DIM + cq * 4;
    float4 acc = {0.f, 0.f, 0.f, 0.f};
#pragma unroll 1
    for (int h = 0; h < 2; ++h) {
      float4 ev[8];
#pragma unroll
      for (int i = 0; i < 8; ++i)
        ev[i] = *(const float4*)(Ep + (size_t)(h * 8 + i) * DIM);
#pragma unroll
      for (int i = 0; i < 8; ++i) {
        float cv = (float)cnt[kseg * 16 + h * 8 + i];
        acc.x = fmaf(cv, ev[i].x, acc.x);
        acc.y = fmaf(cv, ev[i].y, acc.y);
        acc.z = fmaf(cv, ev[i].z, acc.z);
        acc.w = fmaf(cv, ev[i].w, acc.w);
      }
      __builtin_amdgcn_sched_barrier(0);
    }
    *(float4*)&red16[kseg][cq * 4] = acc;
  }
  __syncthreads();
  if (ks == 0) {
    float s = sum16(red16, d);
    s = fmaf((float)cnt[256], embed[(size_t)256 * DIM + d], s);
    sv[d] = s * (1.0f / (float)TT);
  }
  __syncthreads();

  mv8x2(sv, pin_w, kseg, cq, red16);
  __syncthreads();
  if (ks == 0) {
    float base = sum16(red16, d) + pin_b[d];
    basev[d] = base;
    float u = (base + depth_bias[4 * DIM + d] + pch_b[d]) * sigm(level_gate[4]);
    sv[d] = fmaxf(u, 0.f);
  }
  __syncthreads();
  mv8x2(sv, o_w, kseg, cq, red16);
  __syncthreads();
  if (ks == 0) {
    float y = sum16(red16, d) + o_b[d];
    ym[4][d] = y;
    sv[d] = y;
  }
  __syncthreads();
  for (int l = 3; l >= 0; --l) {
    mv8x2(sv, v_w, kseg, cq, red16);
    __syncthreads();
    if (ks == 0) {
      float vv = sum16(red16, d) + v_b[d];
      sv[d] = sigm(depth_gate[l * DIM + d]) * vv;   // uniform softmax -> child = v
    }
    __syncthreads();
    mv8x2(sv, pch_w, kseg, cq, red16);
    __syncthreads();
    if (ks == 0) {
      float t = sum16(red16, d) + pch_b[d];
      float u = (basev[d] + depth_bias[l * DIM + d] + t) * sigm(level_gate[l]);
      sv[d] = fmaxf(u, 0.f);
    }
    __syncthreads();
    mv8x2(sv, o_w, kseg, cq, red16);
    __syncthreads();
    if (ks == 0) {
      float y = sum16(red16, d) + o_b[d];
      ym[l][d] = y;
      sv[d] = y;
    }
    __syncthreads();
  }
  // ---- in_proj, ALL levels in ONE pass over the weights (8-deep batches) ----
  {
    float aq = 0.f;
    float ak0 = 0.f, ak1 = 0.f, ak2 = 0.f, ak3 = 0.f, ak4 = 0.f;
    float av0 = 0.f, av1 = 0.f, av2 = 0.f, av3 = 0.f, av4 = 0.f;
#pragma unroll
    for (int h = 0; h < 8; ++h) {
      int kb = k0 + h * 8;
      float wq[8], wk[8], wv8[8];
#pragma unroll
      for (int i = 0; i < 8; ++i) {
        const float* wrow = in_proj_w + (size_t)(kb + i) * 768;
        wq[i] = wrow[d]; wk[i] = wrow[256 + d]; wv8[i] = wrow[512 + d];
      }
#pragma unroll
      for (int i = 0; i < 8; ++i) {
        float z0 = ym[0][kb + i];
        aq  = fmaf(z0, wq[i], aq);
        ak0 = fmaf(z0, wk[i], ak0);
        av0 = fmaf(z0, wv8[i], av0);
        float z1 = ym[1][kb + i];
        ak1 = fmaf(z1, wk[i], ak1);
        av1 = fmaf(z1, wv8[i], av1);
        float z2 = ym[2][kb + i];
        ak2 = fmaf(z2, wk[i], ak2);
        av2 = fmaf(z2, wv8[i], av2);
        float z3 = ym[3][kb + i];
        ak3 = fmaf(z3, wk[i], ak3);
        av3 = fmaf(z3, wv8[i], av3);
        float z4 = ym[4][kb + i];
        ak4 = fmaf(z4, wk[i], ak4);
        av4 = fmaf(z4, wv8[i], av4);
      }
    }
    red11[ks][0][d] = ak0; red11[ks][1][d] = ak1; red11[ks][2][d] = ak2;
    red11[ks][3][d] = ak3; red11[ks][4][d] = ak4;
    red11[ks][5][d] = av0; red11[ks][6][d] = av1; red11[ks][7][d] = av2;
    red11[ks][8][d] = av3; red11[ks][9][d] = av4;
    red11[ks][10][d] = aq;
  }
  __syncthreads();
  for (int idx = tid; idx < 11 * DIM; idx += 1024) {
    int c = idx >> 8, dd = idx & 255;
    float sum = red11[0][c][dd] + red11[1][c][dd] + red11[2][c][dd] + red11[3][c][dd];
    if (c < 5)       kh[c][dd]     = sum + in_proj_b[256 + dd];
    else if (c < 10) vh[c - 5][dd] = sum + in_proj_b[512 + dd];
    else             q0v[dd]       = sum + in_proj_b[dd];
  }
  __syncthreads();
  {
    int wid = tid >> 6;
    if (wid < 10) {
      int h = wid / 5, l = wid - h * 5;
      int lane = tid & 63;
      float s = q0v[h * 128 + lane] * kh[l][h * 128 + lane];
      s = fmaf(q0v[h * 128 + 64 + lane], kh[l][h * 128 + 64 + lane], s);
      for (int o = 32; o > 0; o >>= 1) s += __shfl_down(s, o, 64);
      if (lane == 0) aw[wid] = s * 0.08838834764831845f;  // 1/sqrt(128)
    }
  }
  __syncthreads();
  if (tid < 2) {
    float m = aw[tid * 5];
    for (int l = 1; l < 5; ++l) m = fmaxf(m, aw[tid * 5 + l]);
    float e[5], ssum = 0.f;
    for (int l = 0; l < 5; ++l) { e[l] = expf(aw[tid * 5 + l] - m); ssum += e[l]; }
    for (int l = 0; l < 5; ++l) aw[tid * 5 + l] = e[l] / ssum;
  }
  __syncthreads();
  if (ks == 0) {
    int h = d >> 7;
    float z2 = 0.f;
    for (int l = 0; l < 5; ++l) z2 = fmaf(aw[h * 5 + l], vh[l][d], z2);
    sv[d] = z2;
  }
  __syncthreads();
  mv8x2(sv, out_proj_w, kseg, cq, red16);
  __syncthreads();
  if (ks == 0) {
    float z2p = sum16(red16, d) + out_proj_b[d];
    zsv[d] = ym[0][d] + z2p;
  }
  __syncthreads();
  float zs = 0.f, df = 0.f, mu = 0.f;
  if (tid < 256) {
    zs = zsv[tid];
    float v = zs;
    for (int o = 32; o > 0; o >>= 1) v += __shfl_down(v, o, 64);
    if ((tid & 63) == 0) redl[tid >> 6] = v;
  }
  __syncthreads();
  if (tid < 256) {
    mu = (redl[0] + redl[1] + redl[2] + redl[3]) * (1.f / 256.f);
    df = zs - mu;
  }
  __syncthreads();
  if (tid < 256) {
    float v = df * df;
    for (int o = 32; o > 0; o >>= 1) v += __shfl_down(v, o, 64);
    if ((tid & 63) == 0) redl[tid >> 6] = v;
  }
  __syncthreads();
  if (tid < 256) {
    float var = (redl[0] + redl[1] + redl[2] + redl[3]) * (1.f / 256.f);
    float zn = df / sqrtf(var + 1e-5f) * ln_g[tid] + ln_b[tid];
    float r = ym[0][tid] + sigm(ic_gate[0]) * zn;
    rootA[b * DIM + tid] = r;
    root2[b * DIM + tid] = r;   // experts atomically add on top
  }
}

// ---- fused MoE: gating + GEMM1 + partial-GEMM2 + combine -------------------
// Blocks 0..63 = 8 experts x 8 tiles of 64 HID cols (unchanged from R7).
// Blocks 64..255 = warm-up streamers for ew1/ew2 (8.4MB, cold every iteration).
// Warmer loads unroll 4 -> 8: 8 independent float4s in flight (2 exposures,
// 32 VGPR - under the 256-thread block's cap) -> warmers finish sooner.
__global__ void __launch_bounds__(256) k_moe(
    const float* __restrict__ rootA,
    const float* __restrict__ gate_w, const float* __restrict__ gate_b,
    const float* __restrict__ ew1, const float* __restrict__ eb1,
    const float* __restrict__ ew2, const float* __restrict__ eb2,
    float* __restrict__ root2) {
  int bx = blockIdx.x;
  int tid = threadIdx.x;
  if (bx >= 64) {
    // warm-up: one 64KB region of ew1/ew2 (128 regions, covered 1.5x)
    int r = (bx - 64) % 128;
    const float* W = (r < 64) ? ew1 + (size_t)r * 16384
                              : ew2 + (size_t)(r - 64) * 16384;
    const float4* src = (const float4*)W + tid;
    float sx = 0.f, sy = 0.f, sz = 0.f, sw = 0.f;
#pragma unroll 8
    for (int i = 0; i < 16; ++i) {
      float4 v = src[i * 256];
      sx += v.x; sy += v.y; sz += v.z; sw += v.w;
    }
    asm volatile("" :: "v"(sx), "v"(sy), "v"(sz), "v"(sw));
    return;
  }
  int e = bx >> 3, jt = bx & 7, j0 = jt * 64;
  int w = tid >> 6, lane = tid & 63;
  __shared__ float rlds[BB * DIM];      // 16KB rootA copy
  __shared__ float gwlds[DIM * NEXP];   // 8KB gate_w copy
  __shared__ float xin[CAP][DIM];
  __shared__ float red[CAP][4][64];
  __shared__ float hloc[CAP][64];
  __shared__ float sc[BB * NEXP];
  __shared__ float gs[BB * TOPK];
  __shared__ int gidx[BB * TOPK];
  __shared__ int stok[CAP];
  __shared__ float swt[CAP];
  for (int idx = tid; idx < BB * DIM / 4; idx += 256)
    *(float4*)&rlds[idx * 4] = *(const float4*)&rootA[idx * 4];
  for (int idx = tid; idx < DIM * NEXP / 4; idx += 256)
    *(float4*)&gwlds[idx * 4] = *(const float4*)&gate_w[idx * 4];
  __syncthreads();
  if (tid < BB * NEXP) {
    int b = tid >> 3, ep = tid & 7;
    float chunk[8];
#pragma unroll
    for (int g = 0; g < 8; ++g) {
      float acc = 0.f;
#pragma unroll 8
      for (int i = 0; i < 32; ++i) {
        int k = g * 32 + i;
        acc = fmaf(rlds[b * DIM + k], gwlds[k * NEXP + ep], acc);
      }
      chunk[g] = acc;
    }
    float s = gate_b[ep];
#pragma unroll
    for (int g = 0; g < 8; ++g) s += chunk[g];
    sc[tid] = s;
  }
  __syncthreads();
  if (tid < BB) {  // top-2 + softmax per batch (identical order to old k_gate)
    int bb = tid;
    int i0 = 0; float v0 = sc[bb * 8 + 0];
    for (int ee = 1; ee < 8; ++ee) { float v = sc[bb * 8 + ee]; if (v > v0) { v0 = v; i0 = ee; } }
    int i1 = -1; float v1 = -1e30f;
    for (int ee = 0; ee < 8; ++ee) {
      if (ee == i0) continue;
      float v = sc[bb * 8 + ee];
      if (v > v1) { v1 = v; i1 = ee; }
    }
    float e1v = expf(v1 - v0);
    float s = 1.f + e1v;
    gs[bb * 2 + 0] = 1.f / s;  gidx[bb * 2 + 0] = i0;
    gs[bb * 2 + 1] = e1v / s;  gidx[bb * 2 + 1] = i1;
  }
  __syncthreads();
  if (tid == 0) {  // top-CAP for own expert: bitmask, value desc / index asc
    unsigned used = 0u;
    for (int s = 0; s < CAP; ++s) {
      int bi = 0; float bv = -1e30f;
      for (int i = 0; i < 32; ++i) {
        if (used & (1u << i)) continue;
        float v = (gidx[i] == e) ? gs[i] : -1.0f;
        if (v > bv) { bv = v; bi = i; }
      }
      used |= (1u << bi);
      stok[s] = bi >> 1;
      swt[s] = bv > 0.f ? bv : 0.f;
    }
  }
  __syncthreads();
  for (int idx = tid; idx < CAP * DIM; idx += 256) {
    int s = idx >> 8, k = idx & 255;
    xin[s][k] = rlds[stok[s] * DIM + k];
  }
  __syncthreads();
  // GEMM1: this block's 64 HID cols (identical order to old k_expert1)
  {
    float a0 = 0.f, a1 = 0.f, a2 = 0.f, a3 = 0.f, a4 = 0.f;
    const float* W = ew1 + (size_t)e * DIM * HID + j0 + lane;  // row k -> +k*HID
    int kbase = w * 64;
#pragma unroll
    for (int h = 0; h < 8; ++h) {
      float wv[8];
#pragma unroll
      for (int i = 0; i < 8; ++i) wv[i] = W[(size_t)(kbase + h * 8 + i) * HID];
#pragma unroll
      for (int i = 0; i < 8; ++i) {
        int k = kbase + h * 8 + i;
        a0 = fmaf(xin[0][k], wv[i], a0);
        a1 = fmaf(xin[1][k], wv[i], a1);
        a2 = fmaf(xin[2][k], wv[i], a2);
        a3 = fmaf(xin[3][k], wv[i], a3);
        a4 = fmaf(xin[4][k], wv[i], a4);
      }
    }
    red[0][w][lane] = a0; red[1][w][lane] = a1; red[2][w][lane] = a2;
    red[3][w][lane] = a3; red[4][w][lane] = a4;
  }
  __syncthreads();
  for (int idx = tid; idx < CAP * 64; idx += 256) {
    int s = idx >> 6, j = idx & 63;
    float sum = red[s][0][j] + red[s][1][j] + red[s][2][j] + red[s][3][j]
              + eb1[e * HID + j0 + j];
    hloc[s][j] = fmaxf(sum, 0.f);
  }
  __syncthreads();
  // partial GEMM2: K = this block's 64 hid cols, d = tid (0..255)
  {
    int d = tid;
    float a0 = 0.f, a1 = 0.f, a2 = 0.f, a3 = 0.f, a4 = 0.f;
    const float* W2 = ew2 + (size_t)e * HID * DIM + (size_t)j0 * DIM + d;
#pragma unroll
    for (int h = 0; h < 8; ++h) {
      float wv[8];
#pragma unroll
      for (int i = 0; i < 8; ++i) wv[i] = W2[(size_t)(h * 8 + i) * DIM];
#pragma unroll
      for (int i = 0; i < 8; ++i) {
        int j = h * 8 + i;
        a0 = fmaf(hloc[0][j], wv[i], a0);
        a1 = fmaf(hloc[1][j], wv[i], a1);
        a2 = fmaf(hloc[2][j], wv[i], a2);
        a3 = fmaf(hloc[3][j], wv[i], a3);
        a4 = fmaf(hloc[4][j], wv[i], a4);
      }
    }
    float bias = (jt == 0) ? eb2[e * DIM + d] : 0.f;
#pragma unroll
    for (int s = 0; s < CAP; ++s) {
      float as = (s == 0) ? a0 : (s == 1) ? a1 : (s == 2) ? a2 : (s == 3) ? a3 : a4;
      float wgt = swt[s];
      if (wgt > 0.f)
        atomicAdd(&root2[stok[s] * DIM + d], (as + bias) * wgt);
    }
  }
}

// ---- logits + fused scatter: grid (257 tokens x 4 rowgroups) x 256 threads --
// R5-proven shape: 1028 blocks keeps the machine latency-tolerant; weights
// (520KB) are L2-resident so redundant reads are cheap. (R6's 16-row/257-block
// variant: 1 block/CU, serial chain 4x longer -> 205us. Reverted.)
__global__ void __launch_bounds__(256) k_logits(
    const float* __restrict__ embed, const float* __restrict__ root2,
    const float* __restrict__ hw1, const float* __restrict__ hb1,
    const float* __restrict__ hw2, const float* __restrict__ hb2,
    const int* __restrict__ bidx, const int* __restrict__ boff,
    float* __restrict__ out) {
  int tok = blockIdx.x, r0 = blockIdx.y * 4;
  int c = threadIdx.x;
  __shared__ float hrow[4][DIM];
  __shared__ float hid[4][DIM];
  __shared__ float tailred[4][17];
  __shared__ float tailv[4];
  {
    float ev = embed[(size_t)tok * DIM + c];
#pragma unroll
    for (int j = 0; j < 4; ++j) hrow[j][c] = ev + root2[(size_t)(r0 + j) * DIM + c];
  }
  __syncthreads();
  // GEMM1: col c over K=256, 4 rows
  {
    float a0 = hb1[c], a1 = a0, a2 = a0, a3 = a0;
    for (int kb = 0; kb < DIM; kb += 8) {
      float wv[8];
#pragma unroll
      for (int i = 0; i < 8; ++i) wv[i] = hw1[(size_t)(kb + i) * DIM + c];
#pragma unroll
      for (int i = 0; i < 8; ++i) {
        int k = kb + i;
        a0 = fmaf(hrow[0][k], wv[i], a0);
        a1 = fmaf(hrow[1][k], wv[i], a1);
        a2 = fmaf(hrow[2][k], wv[i], a2);
        a3 = fmaf(hrow[3][k], wv[i], a3);
      }
    }
    hid[0][c] = fmaxf(a0, 0.f); hid[1][c] = fmaxf(a1, 0.f);
    hid[2][c] = fmaxf(a2, 0.f); hid[3][c] = fmaxf(a3, 0.f);
  }
  __syncthreads();
  // GEMM2: cols 0..255 into registers
  float a0, a1, a2, a3;
  {
    a0 = hb2[c]; a1 = a0; a2 = a0; a3 = a0;
    for (int kb = 0; kb < DIM; kb += 8) {
      float wv[8];
#pragma unroll
      for (int i = 0; i < 8; ++i) wv[i] = hw2[(size_t)(kb + i) * VOCAB + c];
#pragma unroll
      for (int i = 0; i < 8; ++i) {
        int k = kb + i;
        a0 = fmaf(hid[0][k], wv[i], a0);
        a1 = fmaf(hid[1][k], wv[i], a1);
        a2 = fmaf(hid[2][k], wv[i], a2);
        a3 = fmaf(hid[3][k], wv[i], a3);
      }
    }
  }
  // tail column 256: 16-way K-split across first 64 threads
  if (c < 64) {
    int r = c >> 4, seg = c & 15;
    float sum = 0.f;
#pragma unroll 4
    for (int i = 0; i < 16; ++i) {
      int k = seg * 16 + i;
      sum = fmaf(hid[r][k], hw2[(size_t)k * VOCAB + 256], sum);
    }
    tailred[r][seg] = sum;
  }
  __syncthreads();
  if (c < 4) {
    float a = hb2[256];
#pragma unroll
    for (int s = 0; s < 16; ++s) a += tailred[c][s];
    tailv[c] = a;
  }
  __syncthreads();
  // fused scatter: write this row to every matching t (coalesced 1KB rows)
#pragma unroll
  for (int j = 0; j < 4; ++j) {
    int b = r0 + j;
    int s = boff[b * (VOCAB + 1) + tok];
    int e = boff[b * (VOCAB + 1) + tok + 1];
    float aj = (j == 0) ? a0 : (j == 1) ? a1 : (j == 2) ? a2 : a3;
    float tl = tailv[j];
    for (int m = s; m < e; ++m) {
      int t = bidx[b * TT + m];
      size_t base = (size_t)(b * TT + t) * VOCAB;
      out[base + c] = aj;
      if (c == 0) out[base + 256] = tl;
    }
  }
}

extern "C" void kernel_launch(void* const* d_in, const int* in_sizes, int n_in,
                              void* d_out, int out_size, void* d_ws, size_t ws_size,
                              hipStream_t stream) {
  (void)in_sizes; (void)n_in; (void)out_size; (void)ws_size;
  const int*   tokens     = (const int*)d_in[0];
  const float* embed      = (const float*)d_in[1];
  const float* pin_w      = (const float*)d_in[2];
  const float* pin_b      = (const float*)d_in[3];
  const float* pch_w      = (const float*)d_in[4];
  const float* pch_b      = (const float*)d_in[5];
  const float* depth_bias = (const float*)d_in[6];
  // d_in[7..10] = q_w,q_b,k_w,k_b: provably unused (uniform softmax)
  const float* v_w        = (const float*)d_in[11];
  const float* v_b        = (const float*)d_in[12];
  const float* o_w        = (const float*)d_in[13];
  const float* o_b        = (const float*)d_in[14];
  const float* level_gate = (const float*)d_in[15];
  const float* depth_gate = (const float*)d_in[16];
  const float* in_proj_w  = (const float*)d_in[17];
  const float* in_proj_b  = (const float*)d_in[18];
  const float* out_proj_w = (const float*)d_in[19];
  const float* out_proj_b = (const float*)d_in[20];
  const float* ln_g       = (const float*)d_in[21];
  const float* ln_b       = (const float*)d_in[22];
  const float* ic_gate    = (const float*)d_in[23];
  const float* gate_w     = (const float*)d_in[24];
  const float* gate_b     = (const float*)d_in[25];
  const float* ew1        = (const float*)d_in[26];
  const float* eb1        = (const float*)d_in[27];
  const float* ew2        = (const float*)d_in[28];
  const float* eb2        = (const float*)d_in[29];
  const float* hw1        = (const float*)d_in[30];
  const float* hb1        = (const float*)d_in[31];
  const float* hw2        = (const float*)d_in[32];
  const float* hb2        = (const float*)d_in[33];
  float* out = (float*)d_out;

  float* ws      = (float*)d_ws;
  float* rootA   = ws + 4096;            // 4096 floats
  float* root2   = ws + 8192;            // 4096 floats
  int*   bidx    = (int*)(ws + 43136);   // 16*2048 = 32768 ints
  int*   boff    = (int*)(ws + 75904);   // 16*258  =  4128 ints

  k_fractal<<<256, 1024, 0, stream>>>(tokens, embed, pin_w, pin_b, pch_w, pch_b,
                                      depth_bias, v_w, v_b, o_w, o_b, level_gate,
                                      depth_gate, in_proj_w, in_proj_b, out_proj_w,
                                      out_proj_b, ln_g, ln_b, ic_gate, rootA, root2,
                                      bidx, boff);
  k_moe<<<256, 256, 0, stream>>>(rootA, gate_w, gate_b, ew1, eb1,
                                 ew2, eb2, root2);
  k_logits<<<dim3(VOCAB, 4), 256, 0, stream>>>(embed, root2, hw1, hb1, hw2, hb2,
                                               bidx, boff, out);
}

// Round 13
// 229.578 us; speedup vs baseline: 2.1540x; 1.0003x over previous
//
#include <hip/hip_runtime.h>
#include <hip/hip_bf16.h>
#include <math.h>

#define DIM    256
#define DEPTH  5
#define FANOUT 10
#define VOCAB  257
#define BB     16
#define TT     2048
#define NEXP   8
#define HID    512
#define TOPK   2
#define CAP    5   // ceil(16*2/8*1.1)

__device__ __forceinline__ float sigm(float x) { return 1.f / (1.f + expf(-x)); }

// classic matvec partial (shared-sv input) - kept for out_proj step.
__device__ __forceinline__ void mv8x2(const float* sv, const float* __restrict__ W,
                                      int kseg, int cq, float red[16][DIM]) {
  const float* Wp = W + (size_t)kseg * 16 * DIM + cq * 4;
  float4 acc = {0.f, 0.f, 0.f, 0.f};
#pragma unroll 1
  for (int h = 0; h < 2; ++h) {
    float4 wv[8];
#pragma unroll
    for (int i = 0; i < 8; ++i)
      wv[i] = *(const float4*)(Wp + (size_t)(h * 8 + i) * DIM);
#pragma unroll
    for (int i = 0; i < 8; ++i) {
      float s = sv[kseg * 16 + h * 8 + i];
      acc.x = fmaf(s, wv[i].x, acc.x);
      acc.y = fmaf(s, wv[i].y, acc.y);
      acc.z = fmaf(s, wv[i].z, acc.z);
      acc.w = fmaf(s, wv[i].w, acc.w);
    }
    __builtin_amdgcn_sched_barrier(0);
  }
  *(float4*)&red[kseg][cq * 4] = acc;
}

__device__ __forceinline__ float sum16(const float red[16][DIM], int d) {
  float s = 0.f;
#pragma unroll
  for (int g = 0; g < 16; ++g) s += red[g][d];
  return s;
}

// wave-local matvec: input x[kseg*16+j] held in lane j's rv (j<16), broadcast
// via __shfl (compile-time lane -> v_readlane). Writes 16x256 partials to buf.
__device__ __forceinline__ void mvw(float rv, const float* __restrict__ W,
                                    int kseg, int cq, float* buf) {
  const float* Wp = W + (size_t)kseg * 16 * DIM + cq * 4;
  float4 acc = {0.f, 0.f, 0.f, 0.f};
#pragma unroll 1
  for (int h = 0; h < 2; ++h) {
    float4 wv[8];
#pragma unroll
    for (int i = 0; i < 8; ++i)
      wv[i] = *(const float4*)(Wp + (size_t)(h * 8 + i) * DIM);
#pragma unroll
    for (int i = 0; i < 8; ++i) {
      float s = __shfl(rv, h * 8 + i, 64);
      acc.x = fmaf(s, wv[i].x, acc.x);
      acc.y = fmaf(s, wv[i].y, acc.y);
      acc.z = fmaf(s, wv[i].z, acc.z);
      acc.w = fmaf(s, wv[i].w, acc.w);
    }
    __builtin_amdgcn_sched_barrier(0);
  }
  *(float4*)&buf[kseg * DIM + cq * 4] = acc;
}

// wave-local reduce of one column (same g=0..15 order as sum16 -> bit-exact)
__device__ __forceinline__ float redw(const float* buf, int dme) {
  float s = 0.f;
#pragma unroll
  for (int g = 0; g < 16; ++g) s += buf[g * DIM + dme];
  return s;
}

// ------ collapsed fractal + context + root2 init ------------------------------
// R9/R12 base (best 229.7us) + R13 change: chain uses 1 barrier per matvec.
// Each wave reduces its OWN 16-elem slice (redw, bit-exact order), applies the
// elementwise epilogue from LDS-preloaded constants, and feeds the next matvec
// via __shfl - no shared sv, no serial ks==0 consumer, ping-pong partial bufs.
// Grid = 256 blocks, role = bx&7 (XCD id):
//   xcd 0, slot 0..15 : 16 real chains (one XCD -> one L2 holds weights).
//   xcd 0, slot 16..31: warmers (37x64KB weight regions into XCD0's L2).
//   xcd 1, slot 0..15 : token-CSR build. everything else: exit.
__global__ void __launch_bounds__(1024) k_fractal(
    const int* __restrict__ tokens, const float* __restrict__ embed,
    const float* __restrict__ pin_w, const float* __restrict__ pin_b,
    const float* __restrict__ pch_w, const float* __restrict__ pch_b,
    const float* __restrict__ depth_bias,
    const float* __restrict__ v_w, const float* __restrict__ v_b,
    const float* __restrict__ o_w, const float* __restrict__ o_b,
    const float* __restrict__ level_gate, const float* __restrict__ depth_gate,
    const float* __restrict__ in_proj_w, const float* __restrict__ in_proj_b,
    const float* __restrict__ out_proj_w, const float* __restrict__ out_proj_b,
    const float* __restrict__ ln_g, const float* __restrict__ ln_b,
    const float* __restrict__ ic_gate,
    float* __restrict__ rootA, float* __restrict__ root2,
    int* __restrict__ bidx, int* __restrict__ boff) {
  int bx = blockIdx.x;
  int tid = threadIdx.x;
  int xcd = bx & 7, slot = bx >> 3;
  __shared__ int cnt[VOCAB];
  __shared__ float sv[DIM];
  __shared__ float ym[DEPTH][DIM];
  __shared__ float q0v[DIM], kh[DEPTH][DIM], vh[DEPTH][DIM];
  __shared__ float red11[4][11][DIM];   // in_proj reduction; chain ping-pong bufs
  __shared__ float zsv[DIM];
  __shared__ float aw[16];
  __shared__ float redl[8];
  __shared__ int offb[VOCAB + 1];
  __shared__ int woff[VOCAB];
  __shared__ float pre[14][DIM];        // preloaded epilogue constants (14KB)
  __shared__ float lg_s[DEPTH];
  float (*red16)[DIM] = reinterpret_cast<float(*)[DIM]>(&red11[0][0][0]);
  float* bufA = &red11[0][0][0];        // 16KB
  float* bufB = bufA + 4096;            // next 16KB (red11 dead until in_proj)

  if (xcd == 1) {
    if (slot < BB) {
      // ---- token CSR for batch b: off the chain's critical path ----
      int b = slot;
      for (int i = tid; i < VOCAB; i += 1024) cnt[i] = 0;
      __syncthreads();
      for (int t = tid; t < TT; t += 1024) atomicAdd(&cnt[tokens[b * TT + t]], 1);
      __syncthreads();
      if (tid == 0) {
        int a = 0;
        for (int v = 0; v < VOCAB; ++v) { offb[v] = a; a += cnt[v]; }
        offb[VOCAB] = a;              // == TT
      }
      __syncthreads();
      if (tid <= VOCAB) boff[b * (VOCAB + 1) + tid] = offb[tid];
      if (tid < VOCAB) woff[tid] = offb[tid];
      __syncthreads();
      for (int t = tid; t < TT; t += 1024) {
        int tok = tokens[b * TT + t];
        int p = atomicAdd(&woff[tok], 1);
        bidx[b * TT + p] = t;         // bucket order arbitrary; output order-invariant
      }
    }
    return;
  }
  if (xcd != 0) return;
  if (slot >= BB) {
    // ---- warmer: 3 of the 37 64KB weight regions into XCD0's L2 ----
    int w = slot - BB;                // 0..15
    float sx = 0.f, sy = 0.f, sz = 0.f, sw = 0.f;
#pragma unroll 1
    for (int q = 0; q < 3; ++q) {
      int r = w * 3 + q;
      if (r >= 37) break;
      const float* W; int n = 16384;
      if (r < 4)       W = pin_w      + (size_t)r * 16384;
      else if (r < 8)  W = pch_w      + (size_t)(r - 4) * 16384;
      else if (r < 12) W = v_w        + (size_t)(r - 8) * 16384;
      else if (r < 16) W = o_w        + (size_t)(r - 12) * 16384;
      else if (r < 20) W = out_proj_w + (size_t)(r - 16) * 16384;
      else if (r < 32) W = in_proj_w  + (size_t)(r - 20) * 16384;
      else { W = embed + (size_t)(r - 32) * 16384; n = 65792 - (r - 32) * 16384;
             if (n > 16384) n = 16384; }
      const float4* src = (const float4*)W + tid;
#pragma unroll
      for (int k = 0; k < 4; ++k) {
        int p = tid * 4 + k * 4096;
        if (p + 4 <= n) {
          float4 v = src[k * 1024];
          sx += v.x; sy += v.y; sz += v.z; sw += v.w;
        }
      }
    }
    asm volatile("" :: "v"(sx), "v"(sy), "v"(sz), "v"(sw));
    return;
  }

  int b = slot;
  int d = tid & 255;
  int ks = tid >> 8;       // 0..3 (in_proj layout)
  int k0 = ks * 64;
  int kseg = tid >> 6;     // 0..15 (matvec layout)
  int cq = tid & 63;
  int lane = tid & 63;
  int dme = kseg * 16 + (lane & 15);   // this wave's slice element

  // ---- histogram + epilogue-constant preload (overlapped) ----
  for (int i = tid; i < VOCAB; i += 1024) cnt[i] = 0;
  for (int i = tid; i < DIM; i += 1024) {
    pre[0][i] = pin_b[i]; pre[1][i] = o_b[i];
    pre[2][i] = pch_b[i]; pre[3][i] = v_b[i];
    pre[13][i] = embed[(size_t)256 * DIM + i];
  }
  for (int i = tid; i < 5 * DIM; i += 1024) pre[4 + (i >> 8)][i & 255] = depth_bias[i];
  for (int i = tid; i < 4 * DIM; i += 1024) pre[9 + (i >> 8)][i & 255] = sigm(depth_gate[i]);
  if (tid < DEPTH) lg_s[tid] = sigm(level_gate[tid]);
  __syncthreads();
  for (int t = tid; t < TT; t += 1024) atomicAdd(&cnt[tokens[b * TT + t]], 1);
  __syncthreads();
  // ---- context matvec: (histogram @ embed), partials -> bufA ----
  {
    const float* Ep = embed + (size_t)kseg * 16 * DIM + cq * 4;
    float4 acc = {0.f, 0.f, 0.f, 0.f};
#pragma unroll 1
    for (int h = 0; h < 2; ++h) {
      float4 ev[8];
#pragma unroll
      for (int i = 0; i < 8; ++i)
        ev[i] = *(const float4*)(Ep + (size_t)(h * 8 + i) * DIM);
#pragma unroll
      for (int i = 0; i < 8; ++i) {
        float cv = (float)cnt[kseg * 16 + h * 8 + i];
        acc.x = fmaf(cv, ev[i].x, acc.x);
        acc.y = fmaf(cv, ev[i].y, acc.y);
        acc.z = fmaf(cv, ev[i].z, acc.z);
        acc.w = fmaf(cv, ev[i].w, acc.w);
      }
      __builtin_amdgcn_sched_barrier(0);
    }
    *(float4*)&bufA[kseg * DIM + cq * 4] = acc;
  }
  __syncthreads();                       // bufA ready
  // ---- chain: 1 barrier per matvec, strict buffer alternation ----
  float* cur = bufB; float* prv = bufA;  // cur = buffer the NEXT mv writes
  float rv, base_r;
  {
    float s = redw(prv, dme);
    s = fmaf((float)cnt[256], pre[13][dme], s);
    rv = s * (1.0f / (float)TT);         // context value (== old sv[d])
  }
  mvw(rv, pin_w, kseg, cq, cur);
  __syncthreads();
  { float* t = cur; cur = prv; prv = t; }
  {
    base_r = redw(prv, dme) + pre[0][dme];
    float u = (base_r + pre[8][dme] + pre[2][dme]) * lg_s[4];
    rv = fmaxf(u, 0.f);
  }
  mvw(rv, o_w, kseg, cq, cur);
  __syncthreads();
  { float* t = cur; cur = prv; prv = t; }
  {
    float y = redw(prv, dme) + pre[1][dme];
    if (lane < 16) ym[4][dme] = y;
    rv = y;
  }
#pragma unroll 1
  for (int l = 3; l >= 0; --l) {
    mvw(rv, v_w, kseg, cq, cur);
    __syncthreads();
    { float* t = cur; cur = prv; prv = t; }
    rv = pre[9 + l][dme] * (redw(prv, dme) + pre[3][dme]);  // uniform softmax -> child = v
    mvw(rv, pch_w, kseg, cq, cur);
    __syncthreads();
    { float* t = cur; cur = prv; prv = t; }
    {
      float t2 = redw(prv, dme) + pre[2][dme];
      float u = (base_r + pre[4 + l][dme] + t2) * lg_s[l];
      rv = fmaxf(u, 0.f);
    }
    mvw(rv, o_w, kseg, cq, cur);
    __syncthreads();
    { float* t = cur; cur = prv; prv = t; }
    {
      float y = redw(prv, dme) + pre[1][dme];
      if (lane < 16) ym[l][dme] = y;
      rv = y;
    }
  }
  __syncthreads();   // ym fully visible; chain scratch (red11) now reusable
  // ---- in_proj, ALL levels in ONE pass over the weights (8-deep batches) ----
  {
    float aq = 0.f;
    float ak0 = 0.f, ak1 = 0.f, ak2 = 0.f, ak3 = 0.f, ak4 = 0.f;
    float av0 = 0.f, av1 = 0.f, av2 = 0.f, av3 = 0.f, av4 = 0.f;
#pragma unroll
    for (int h = 0; h < 8; ++h) {
      int kb = k0 + h * 8;
      float wq[8], wk[8], wv8[8];
#pragma unroll
      for (int i = 0; i < 8; ++i) {
        const float* wrow = in_proj_w + (size_t)(kb + i) * 768;
        wq[i] = wrow[d]; wk[i] = wrow[256 + d]; wv8[i] = wrow[512 + d];
      }
#pragma unroll
      for (int i = 0; i < 8; ++i) {
        float z0 = ym[0][kb + i];
        aq  = fmaf(z0, wq[i], aq);
        ak0 = fmaf(z0, wk[i], ak0);
        av0 = fmaf(z0, wv8[i], av0);
        float z1 = ym[1][kb + i];
        ak1 = fmaf(z1, wk[i], ak1);
        av1 = fmaf(z1, wv8[i], av1);
        float z2 = ym[2][kb + i];
        ak2 = fmaf(z2, wk[i], ak2);
        av2 = fmaf(z2, wv8[i], av2);
        float z3 = ym[3][kb + i];
        ak3 = fmaf(z3, wk[i], ak3);
        av3 = fmaf(z3, wv8[i], av3);
        float z4 = ym[4][kb + i];
        ak4 = fmaf(z4, wk[i], ak4);
        av4 = fmaf(z4, wv8[i], av4);
      }
    }
    red11[ks][0][d] = ak0; red11[ks][1][d] = ak1; red11[ks][2][d] = ak2;
    red11[ks][3][d] = ak3; red11[ks][4][d] = ak4;
    red11[ks][5][d] = av0; red11[ks][6][d] = av1; red11[ks][7][d] = av2;
    red11[ks][8][d] = av3; red11[ks][9][d] = av4;
    red11[ks][10][d] = aq;
  }
  __syncthreads();
  for (int idx = tid; idx < 11 * DIM; idx += 1024) {
    int c = idx >> 8, dd = idx & 255;
    float sum = red11[0][c][dd] + red11[1][c][dd] + red11[2][c][dd] + red11[3][c][dd];
    if (c < 5)       kh[c][dd]     = sum + in_proj_b[256 + dd];
    else if (c < 10) vh[c - 5][dd] = sum + in_proj_b[512 + dd];
    else             q0v[dd]       = sum + in_proj_b[dd];
  }
  __syncthreads();
  {
    int wid = tid >> 6;
    if (wid < 10) {
      int h = wid / 5, l = wid - h * 5;
      int ln2 = tid & 63;
      float s = q0v[h * 128 + ln2] * kh[l][h * 128 + ln2];
      s = fmaf(q0v[h * 128 + 64 + ln2], kh[l][h * 128 + 64 + ln2], s);
      for (int o = 32; o > 0; o >>= 1) s += __shfl_down(s, o, 64);
      if (ln2 == 0) aw[wid] = s * 0.08838834764831845f;  // 1/sqrt(128)
    }
  }
  __syncthreads();
  if (tid < 2) {
    float m = aw[tid * 5];
    for (int l = 1; l < 5; ++l) m = fmaxf(m, aw[tid * 5 + l]);
    float e[5], ssum = 0.f;
    for (int l = 0; l < 5; ++l) { e[l] = expf(aw[tid * 5 + l] - m); ssum += e[l]; }
    for (int l = 0; l < 5; ++l) aw[tid * 5 + l] = e[l] / ssum;
  }
  __syncthreads();
  if (ks == 0) {
    int h = d >> 7;
    float z2 = 0.f;
    for (int l = 0; l < 5; ++l) z2 = fmaf(aw[h * 5 + l], vh[l][d], z2);
    sv[d] = z2;
  }
  __syncthreads();
  mv8x2(sv, out_proj_w, kseg, cq, red16);
  __syncthreads();
  if (ks == 0) {
    float z2p = sum16(red16, d) + out_proj_b[d];
    zsv[d] = ym[0][d] + z2p;
  }
  __syncthreads();
  float zs = 0.f, df = 0.f, mu = 0.f;
  if (tid < 256) {
    zs = zsv[tid];
    float v = zs;
    for (int o = 32; o > 0; o >>= 1) v += __shfl_down(v, o, 64);
    if ((tid & 63) == 0) redl[tid >> 6] = v;
  }
  __syncthreads();
  if (tid < 256) {
    mu = (redl[0] + redl[1] + redl[2] + redl[3]) * (1.f / 256.f);
    df = zs - mu;
  }
  __syncthreads();
  if (tid < 256) {
    float v = df * df;
    for (int o = 32; o > 0; o >>= 1) v += __shfl_down(v, o, 64);
    if ((tid & 63) == 0) redl[tid >> 6] = v;
  }
  __syncthreads();
  if (tid < 256) {
    float var = (redl[0] + redl[1] + redl[2] + redl[3]) * (1.f / 256.f);
    float zn = df / sqrtf(var + 1e-5f) * ln_g[tid] + ln_b[tid];
    float r = ym[0][tid] + sigm(ic_gate[0]) * zn;
    rootA[b * DIM + tid] = r;
    root2[b * DIM + tid] = r;   // experts atomically add on top
  }
}

// ---- fused MoE: gating + GEMM1 + partial-GEMM2 + combine -------------------
// Blocks 0..63 = 8 experts x 8 tiles of 64 HID cols. Blocks 64..255 = warm-up
// streamers for ew1/ew2 (8.4MB, cold every iteration).
__global__ void __launch_bounds__(256) k_moe(
    const float* __restrict__ rootA,
    const float* __restrict__ gate_w, const float* __restrict__ gate_b,
    const float* __restrict__ ew1, const float* __restrict__ eb1,
    const float* __restrict__ ew2, const float* __restrict__ eb2,
    float* __restrict__ root2) {
  int bx = blockIdx.x;
  int tid = threadIdx.x;
  if (bx >= 64) {
    // warm-up: one 64KB region of ew1/ew2 (128 regions, covered 1.5x)
    int r = (bx - 64) % 128;
    const float* W = (r < 64) ? ew1 + (size_t)r * 16384
                              : ew2 + (size_t)(r - 64) * 16384;
    const float4* src = (const float4*)W + tid;
    float sx = 0.f, sy = 0.f, sz = 0.f, sw = 0.f;
#pragma unroll 8
    for (int i = 0; i < 16; ++i) {
      float4 v = src[i * 256];
      sx += v.x; sy += v.y; sz += v.z; sw += v.w;
    }
    asm volatile("" :: "v"(sx), "v"(sy), "v"(sz), "v"(sw));
    return;
  }
  int e = bx >> 3, jt = bx & 7, j0 = jt * 64;
  int w = tid >> 6, lane = tid & 63;
  __shared__ float rlds[BB * DIM];      // 16KB rootA copy
  __shared__ float gwlds[DIM * NEXP];   // 8KB gate_w copy
  __shared__ float xin[CAP][DIM];
  __shared__ float red[CAP][4][64];
  __shared__ float hloc[CAP][64];
  __shared__ float sc[BB * NEXP];
  __shared__ float gs[BB * TOPK];
  __shared__ int gidx[BB * TOPK];
  __shared__ int stok[CAP];
  __shared__ float swt[CAP];
  for (int idx = tid; idx < BB * DIM / 4; idx += 256)
    *(float4*)&rlds[idx * 4] = *(const float4*)&rootA[idx * 4];
  for (int idx = tid; idx < DIM * NEXP / 4; idx += 256)
    *(float4*)&gwlds[idx * 4] = *(const float4*)&gate_w[idx * 4];
  __syncthreads();
  if (tid < BB * NEXP) {
    int b = tid >> 3, ep = tid & 7;
    float chunk[8];
#pragma unroll
    for (int g = 0; g < 8; ++g) {
      float acc = 0.f;
#pragma unroll 8
      for (int i = 0; i < 32; ++i) {
        int k = g * 32 + i;
        acc = fmaf(rlds[b * DIM + k], gwlds[k * NEXP + ep], acc);
      }
      chunk[g] = acc;
    }
    float s = gate_b[ep];
#pragma unroll
    for (int g = 0; g < 8; ++g) s += chunk[g];
    sc[tid] = s;
  }
  __syncthreads();
  if (tid < BB) {  // top-2 + softmax per batch (identical order to old k_gate)
    int bb = tid;
    int i0 = 0; float v0 = sc[bb * 8 + 0];
    for (int ee = 1; ee < 8; ++ee) { float v = sc[bb * 8 + ee]; if (v > v0) { v0 = v; i0 = ee; } }
    int i1 = -1; float v1 = -1e30f;
    for (int ee = 0; ee < 8; ++ee) {
      if (ee == i0) continue;
      float v = sc[bb * 8 + ee];
      if (v > v1) { v1 = v; i1 = ee; }
    }
    float e1v = expf(v1 - v0);
    float s = 1.f + e1v;
    gs[bb * 2 + 0] = 1.f / s;  gidx[bb * 2 + 0] = i0;
    gs[bb * 2 + 1] = e1v / s;  gidx[bb * 2 + 1] = i1;
  }
  __syncthreads();
  if (tid == 0) {  // top-CAP for own expert: bitmask, value desc / index asc
    unsigned used = 0u;
    for (int s = 0; s < CAP; ++s) {
      int bi = 0; float bv = -1e30f;
      for (int i = 0; i < 32; ++i) {
        if (used & (1u << i)) continue;
        float v = (gidx[i] == e) ? gs[i] : -1.0f;
        if (v > bv) { bv = v; bi = i; }
      }
      used |= (1u << bi);
      stok[s] = bi >> 1;
      swt[s] = bv > 0.f ? bv : 0.f;
    }
  }
  __syncthreads();
  for (int idx = tid; idx < CAP * DIM; idx += 256) {
    int s = idx >> 8, k = idx & 255;
    xin[s][k] = rlds[stok[s] * DIM + k];
  }
  __syncthreads();
  // GEMM1: this block's 64 HID cols (identical order to old k_expert1)
  {
    float a0 = 0.f, a1 = 0.f, a2 = 0.f, a3 = 0.f, a4 = 0.f;
    const float* W = ew1 + (size_t)e * DIM * HID + j0 + lane;  // row k -> +k*HID
    int kbase = w * 64;
#pragma unroll
    for (int h = 0; h < 8; ++h) {
      float wv[8];
#pragma unroll
      for (int i = 0; i < 8; ++i) wv[i] = W[(size_t)(kbase + h * 8 + i) * HID];
#pragma unroll
      for (int i = 0; i < 8; ++i) {
        int k = kbase + h * 8 + i;
        a0 = fmaf(xin[0][k], wv[i], a0);
        a1 = fmaf(xin[1][k], wv[i], a1);
        a2 = fmaf(xin[2][k], wv[i], a2);
        a3 = fmaf(xin[3][k], wv[i], a3);
        a4 = fmaf(xin[4][k], wv[i], a4);
      }
    }
    red[0][w][lane] = a0; red[1][w][lane] = a1; red[2][w][lane] = a2;
    red[3][w][lane] = a3; red[4][w][lane] = a4;
  }
  __syncthreads();
  for (int idx = tid; idx < CAP * 64; idx += 256) {
    int s = idx >> 6, j = idx & 63;
    float sum = red[s][0][j] + red[s][1][j] + red[s][2][j] + red[s][3][j]
              + eb1[e * HID + j0 + j];
    hloc[s][j] = fmaxf(sum, 0.f);
  }
  __syncthreads();
  // partial GEMM2: K = this block's 64 hid cols, d = tid (0..255)
  {
    int d = tid;
    float a0 = 0.f, a1 = 0.f, a2 = 0.f, a3 = 0.f, a4 = 0.f;
    const float* W2 = ew2 + (size_t)e * HID * DIM + (size_t)j0 * DIM + d;
#pragma unroll
    for (int h = 0; h < 8; ++h) {
      float wv[8];
#pragma unroll
      for (int i = 0; i < 8; ++i) wv[i] = W2[(size_t)(h * 8 + i) * DIM];
#pragma unroll
      for (int i = 0; i < 8; ++i) {
        int j = h * 8 + i;
        a0 = fmaf(hloc[0][j], wv[i], a0);
        a1 = fmaf(hloc[1][j], wv[i], a1);
        a2 = fmaf(hloc[2][j], wv[i], a2);
        a3 = fmaf(hloc[3][j], wv[i], a3);
        a4 = fmaf(hloc[4][j], wv[i], a4);
      }
    }
    float bias = (jt == 0) ? eb2[e * DIM + d] : 0.f;
#pragma unroll
    for (int s = 0; s < CAP; ++s) {
      float as = (s == 0) ? a0 : (s == 1) ? a1 : (s == 2) ? a2 : (s == 3) ? a3 : a4;
      float wgt = swt[s];
      if (wgt > 0.f)
        atomicAdd(&root2[stok[s] * DIM + d], (as + bias) * wgt);
    }
  }
}

// ---- logits + fused scatter: grid (257 tokens x 4 rowgroups) x 256 threads --
// R5-proven shape: 1028 blocks keeps the machine latency-tolerant; weights
// (520KB) are L2-resident so redundant reads are cheap.
__global__ void __launch_bounds__(256) k_logits(
    const float* __restrict__ embed, const float* __restrict__ root2,
    const float* __restrict__ hw1, const float* __restrict__ hb1,
    const float* __restrict__ hw2, const float* __restrict__ hb2,
    const int* __restrict__ bidx, const int* __restrict__ boff,
    float* __restrict__ out) {
  int tok = blockIdx.x, r0 = blockIdx.y * 4;
  int c = threadIdx.x;
  __shared__ float hrow[4][DIM];
  __shared__ float hid[4][DIM];
  __shared__ float tailred[4][17];
  __shared__ float tailv[4];
  {
    float ev = embed[(size_t)tok * DIM + c];
#pragma unroll
    for (int j = 0; j < 4; ++j) hrow[j][c] = ev + root2[(size_t)(r0 + j) * DIM + c];
  }
  __syncthreads();
  // GEMM1: col c over K=256, 4 rows
  {
    float a0 = hb1[c], a1 = a0, a2 = a0, a3 = a0;
    for (int kb = 0; kb < DIM; kb += 8) {
      float wv[8];
#pragma unroll
      for (int i = 0; i < 8; ++i) wv[i] = hw1[(size_t)(kb + i) * DIM + c];
#pragma unroll
      for (int i = 0; i < 8; ++i) {
        int k = kb + i;
        a0 = fmaf(hrow[0][k], wv[i], a0);
        a1 = fmaf(hrow[1][k], wv[i], a1);
        a2 = fmaf(hrow[2][k], wv[i], a2);
        a3 = fmaf(hrow[3][k], wv[i], a3);
      }
    }
    hid[0][c] = fmaxf(a0, 0.f); hid[1][c] = fmaxf(a1, 0.f);
    hid[2][c] = fmaxf(a2, 0.f); hid[3][c] = fmaxf(a3, 0.f);
  }
  __syncthreads();
  // GEMM2: cols 0..255 into registers
  float a0, a1, a2, a3;
  {
    a0 = hb2[c]; a1 = a0; a2 = a0; a3 = a0;
    for (int kb = 0; kb < DIM; kb += 8) {
      float wv[8];
#pragma unroll
      for (int i = 0; i < 8; ++i) wv[i] = hw2[(size_t)(kb + i) * VOCAB + c];
#pragma unroll
      for (int i = 0; i < 8; ++i) {
        int k = kb + i;
        a0 = fmaf(hid[0][k], wv[i], a0);
        a1 = fmaf(hid[1][k], wv[i], a1);
        a2 = fmaf(hid[2][k], wv[i], a2);
        a3 = fmaf(hid[3][k], wv[i], a3);
      }
    }
  }
  // tail column 256: 16-way K-split across first 64 threads
  if (c < 64) {
    int r = c >> 4, seg = c & 15;
    float sum = 0.f;
#pragma unroll 4
    for (int i = 0; i < 16; ++i) {
      int k = seg * 16 + i;
      sum = fmaf(hid[r][k], hw2[(size_t)k * VOCAB + 256], sum);
    }
    tailred[r][seg] = sum;
  }
  __syncthreads();
  if (c < 4) {
    float a = hb2[256];
#pragma unroll
    for (int s = 0; s < 16; ++s) a += tailred[c][s];
    tailv[c] = a;
  }
  __syncthreads();
  // fused scatter: write this row to every matching t (coalesced 1KB rows)
#pragma unroll
  for (int j = 0; j < 4; ++j) {
    int b = r0 + j;
    int s = boff[b * (VOCAB + 1) + tok];
    int e = boff[b * (VOCAB + 1) + tok + 1];
    float aj = (j == 0) ? a0 : (j == 1) ? a1 : (j == 2) ? a2 : a3;
    float tl = tailv[j];
    for (int m = s; m < e; ++m) {
      int t = bidx[b * TT + m];
      size_t base = (size_t)(b * TT + t) * VOCAB;
      out[base + c] = aj;
      if (c == 0) out[base + 256] = tl;
    }
  }
}

extern "C" void kernel_launch(void* const* d_in, const int* in_sizes, int n_in,
                              void* d_out, int out_size, void* d_ws, size_t ws_size,
                              hipStream_t stream) {
  (void)in_sizes; (void)n_in; (void)out_size; (void)ws_size;
  const int*   tokens     = (const int*)d_in[0];
  const float* embed      = (const float*)d_in[1];
  const float* pin_w      = (const float*)d_in[2];
  const float* pin_b      = (const float*)d_in[3];
  const float* pch_w      = (const float*)d_in[4];
  const float* pch_b      = (const float*)d_in[5];
  const float* depth_bias = (const float*)d_in[6];
  // d_in[7..10] = q_w,q_b,k_w,k_b: provably unused (uniform softmax)
  const float* v_w        = (const float*)d_in[11];
  const float* v_b        = (const float*)d_in[12];
  const float* o_w        = (const float*)d_in[13];
  const float* o_b        = (const float*)d_in[14];
  const float* level_gate = (const float*)d_in[15];
  const float* depth_gate = (const float*)d_in[16];
  const float* in_proj_w  = (const float*)d_in[17];
  const float* in_proj_b  = (const float*)d_in[18];
  const float* out_proj_w = (const float*)d_in[19];
  const float* out_proj_b = (const float*)d_in[20];
  const float* ln_g       = (const float*)d_in[21];
  const float* ln_b       = (const float*)d_in[22];
  const float* ic_gate    = (const float*)d_in[23];
  const float* gate_w     = (const float*)d_in[24];
  const float* gate_b     = (const float*)d_in[25];
  const float* ew1        = (const float*)d_in[26];
  const float* eb1        = (const float*)d_in[27];
  const float* ew2        = (const float*)d_in[28];
  const float* eb2        = (const float*)d_in[29];
  const float* hw1        = (const float*)d_in[30];
  const float* hb1        = (const float*)d_in[31];
  const float* hw2        = (const float*)d_in[32];
  const float* hb2        = (const float*)d_in[33];
  float* out = (float*)d_out;

  float* ws      = (float*)d_ws;
  float* rootA   = ws + 4096;            // 4096 floats
  float* root2   = ws + 8192;            // 4096 floats
  int*   bidx    = (int*)(ws + 43136);   // 16*2048 = 32768 ints
  int*   boff    = (int*)(ws + 75904);   // 16*258  =  4128 ints

  k_fractal<<<256, 1024, 0, stream>>>(tokens, embed, pin_w, pin_b, pch_w, pch_b,
                                      depth_bias, v_w, v_b, o_w, o_b, level_gate,
                                      depth_gate, in_proj_w, in_proj_b, out_proj_w,
                                      out_proj_b, ln_g, ln_b, ic_gate, rootA, root2,
                                      bidx, boff);
  k_moe<<<256, 256, 0, stream>>>(rootA, gate_w, gate_b, ew1, eb1,
                                 ew2, eb2, root2);
  k_logits<<<dim3(VOCAB, 4), 256, 0, stream>>>(embed, root2, hw1, hb1, hw2, hb2,
                                               bidx, boff, out);
}